// Round 1
// baseline (465.176 us; speedup 1.0000x reference)
//
#include <hip/hip_runtime.h>
#include <stdint.h>
#include <string.h>

// ContextualAttention on MI355X.
// Pipeline:
//  k_down:    x -> (bf16x3 packed F3a/F3b for Gram GEMM) + per-pixel sumsq S
//  k_mask:    mask -> 2x2 avg-pooled md
//  k_mmnorm:  md,S -> mm (valid-patch mask), ninv (1/patch-norm)
//  k_xpack:   x -> XpT[j=(a,b,c)][l=(p,q)] bf16 (deconv weights, transposed for GEMM B)
//  gemm_bt:   U = F3a . F3b^T   (Gram matrix, fp32-accurate via bf16x3)
//  k_patchsum:V[hw][pq] = 9-tap diag stencil of U * ninv[pq]
//  k_fuse1:   U = 3-tap flat-diag stencil of V
//  k_fuse2:   V = 3-tap transposed-flat-diag stencil of U
//  k_softmax: A(bf16) = softmax-with-mask(V)
//  gemm_bt:   P = A . XpT^T
//  k_scatter: out = parity-gather of P / 4

namespace {

constexpr int B_ = 4;
constexpr int H_ = 96;
constexpr int W_ = 96;
constexpr int C_ = 128;
constexpr int h_ = 48;
constexpr int L_ = 2304;   // h_*h_
constexpr int N9_ = 1152;  // 9*C_
constexpr int K3_ = 384;   // 3*C_  bf16x3 packed K
constexpr float SCALE_ = 10.0f;
constexpr float EPS_ = 1e-4f;

typedef unsigned short u16;
typedef __attribute__((ext_vector_type(8))) short bfrag8;   // 8 bf16 (4 VGPRs)
typedef __attribute__((ext_vector_type(4))) float f32x4;    // 4 fp32 acc

__device__ __forceinline__ u16 f2bf(float f) {
  // round-to-nearest-even bf16 (finite inputs only)
  uint32_t x;
  __builtin_memcpy(&x, &f, 4);
  uint32_t lsb = (x >> 16) & 1u;
  x += 0x7fffu + lsb;
  return (u16)(x >> 16);
}
__device__ __forceinline__ float bf2f(u16 u) {
  uint32_t v = ((uint32_t)u) << 16;
  float f;
  __builtin_memcpy(&f, &v, 4);
  return f;
}

// ---- downscale (2x2 avg) + bf16x3 pack + per-pixel sum of squares -------
// grid: B_*L_ blocks of 128 threads (one block per half-res pixel)
__global__ __launch_bounds__(128) void k_down(const float* __restrict__ x,
                                              u16* __restrict__ F3a,
                                              u16* __restrict__ F3b,
                                              float* __restrict__ S) {
  int blk = blockIdx.x;
  int b = blk / L_, l = blk % L_;
  int p = l / h_, q = l % h_;
  int c = threadIdx.x;
  const float* xb = x + (((size_t)b * H_ + 2 * p) * W_ + 2 * q) * C_ + c;
  float v = 0.25f * (xb[0] + xb[C_] + xb[(size_t)W_ * C_] + xb[(size_t)W_ * C_ + C_]);
  u16 hi = f2bf(v);
  u16 lo = f2bf(v - bf2f(hi));
  size_t base = ((size_t)b * L_ + l) * K3_;
  // A-side: [hi, hi, lo]; B-side: [hi, lo, hi] -> A.B^T = hi.hi + hi.lo + lo.hi
  F3a[base + c] = hi; F3a[base + 128 + c] = hi; F3a[base + 256 + c] = lo;
  F3b[base + c] = hi; F3b[base + 128 + c] = lo; F3b[base + 256 + c] = hi;
  __shared__ float red[128];
  red[c] = v * v;
  __syncthreads();
  for (int s2 = 64; s2 > 0; s2 >>= 1) {
    if (c < s2) red[c] += red[c + s2];
    __syncthreads();
  }
  if (c == 0) S[(size_t)b * L_ + l] = red[0];
}

// ---- mask 2x2 avg-pool --------------------------------------------------
__global__ __launch_bounds__(256) void k_mask(const float* __restrict__ mask,
                                              float* __restrict__ md) {
  int i = blockIdx.x * 256 + threadIdx.x;   // b*L_ + l
  int b = i / L_, l = i % L_, p = l / h_, q = l % h_;
  const float* mb = mask + ((size_t)b * H_ + 2 * p) * W_ + 2 * q;
  md[i] = 0.25f * (mb[0] + mb[1] + mb[W_] + mb[W_ + 1]);
}

// ---- valid-patch mask + 1/patch-norm ------------------------------------
__global__ __launch_bounds__(256) void k_mmnorm(const float* __restrict__ S,
                                                const float* __restrict__ md,
                                                float* __restrict__ mm,
                                                float* __restrict__ ninv) {
  int i = blockIdx.x * 256 + threadIdx.x;
  int b = i / L_, l = i % L_, p = l / h_, q = l % h_;
  float ssum = 0.f, msum = 0.f;
  for (int a = 0; a < 3; a++) {
    int rp = p - 1 + a;
    if ((unsigned)rp >= (unsigned)h_) continue;
    for (int bb = 0; bb < 3; bb++) {
      int rq = q - 1 + bb;
      if ((unsigned)rq >= (unsigned)h_) continue;
      int idx = b * L_ + rp * h_ + rq;
      ssum += S[idx];
      msum += md[idx];
    }
  }
  mm[i] = (msum == 0.f) ? 1.f : 0.f;
  float n = fmaxf(sqrtf(ssum), EPS_);
  ninv[i] = 1.f / n;
}

// ---- pack deconv weights transposed: XpT[bz][j=(a,bb,c)][l=(p,q)] -------
// LDS-tiled transpose: 32 l x 64 j per block. grid (L_/32, N9_/64, G)
__global__ __launch_bounds__(256) void k_xpack(const float* __restrict__ x,
                                               u16* __restrict__ XpT) {
  int lt = blockIdx.x * 32, jt = blockIdx.y * 64, bz = blockIdx.z;
  __shared__ u16 tile[32][65];
  int t = threadIdx.x;
  int jj = t & 63, lq = t >> 6;   // 4 l's per pass
  for (int pass = 0; pass < 8; ++pass) {
    int ll = pass * 4 + lq;
    int l = lt + ll;
    int p = l / h_, q = l % h_;
    int j = jt + jj;
    int a = j / 384, rem = j % 384, bb = rem / 128, c = rem % 128;
    int gy = 2 * p + a, gx = 2 * q + bb;
    float v = 0.f;
    if (gy < H_ && gx < W_) v = x[(((size_t)bz * H_ + gy) * W_ + gx) * C_ + c];
    tile[ll][jj] = f2bf(v);
  }
  __syncthreads();
  int lw = t & 31, jq = t >> 5;   // 8 j's per pass
  for (int pass = 0; pass < 8; ++pass) {
    int j2 = pass * 8 + jq;
    XpT[((size_t)bz * N9_ + jt + j2) * L_ + lt + lw] = tile[lw][j2];
  }
}

// ---- MFMA GEMM: C[m][n] = sum_k A[m][k]*B[n][k], all dims %128/%32 == 0 --
// 128x128 tile, 4 waves (2x2), 16x16x32 bf16 MFMA, BK=32, reg-staged LDS.
__global__ __launch_bounds__(256) void gemm_bt(const u16* __restrict__ A,
                                               const u16* __restrict__ B,
                                               float* __restrict__ C,
                                               int M, int N, int Kd,
                                               size_t sA, size_t sB, size_t sC) {
  const u16* Ab = A + (size_t)blockIdx.z * sA;
  const u16* Bb = B + (size_t)blockIdx.z * sB;
  float* Cb = C + (size_t)blockIdx.z * sC;
  int m0 = blockIdx.y * 128, n0 = blockIdx.x * 128;
  // padded rows: 32 payload + 8 pad bf16 -> 80B row stride, conflict-free b128 reads
  __shared__ u16 As[128 * 40];
  __shared__ u16 Bs[128 * 40];
  int t = threadIdx.x;
  int lane = t & 63, wv = t >> 6, wr = wv >> 1, wc = wv & 1;
  int mrow = lane & 15, kg = lane >> 4;
  f32x4 acc[4][4];
#pragma unroll
  for (int i = 0; i < 4; i++)
#pragma unroll
    for (int j = 0; j < 4; j++) acc[i][j] = (f32x4)(0.0f);

  int row = t >> 2, kc = t & 3;          // staging: thread -> (row, 16B chunk)
  for (int k0 = 0; k0 < Kd; k0 += 32) {
    bfrag8 av0 = *(const bfrag8*)(Ab + (size_t)(m0 + row) * Kd + k0 + kc * 8);
    bfrag8 av1 = *(const bfrag8*)(Ab + (size_t)(m0 + 64 + row) * Kd + k0 + kc * 8);
    bfrag8 bv0 = *(const bfrag8*)(Bb + (size_t)(n0 + row) * Kd + k0 + kc * 8);
    bfrag8 bv1 = *(const bfrag8*)(Bb + (size_t)(n0 + 64 + row) * Kd + k0 + kc * 8);
    __syncthreads();   // previous iter's frag reads done
    *(bfrag8*)&As[(row)*40 + kc * 8] = av0;
    *(bfrag8*)&As[(row + 64) * 40 + kc * 8] = av1;
    *(bfrag8*)&Bs[(row)*40 + kc * 8] = bv0;
    *(bfrag8*)&Bs[(row + 64) * 40 + kc * 8] = bv1;
    __syncthreads();
    bfrag8 af[4], bf[4];
#pragma unroll
    for (int i = 0; i < 4; i++)
      af[i] = *(const bfrag8*)&As[(wr * 64 + i * 16 + mrow) * 40 + kg * 8];
#pragma unroll
    for (int i = 0; i < 4; i++)
      bf[i] = *(const bfrag8*)&Bs[(wc * 64 + i * 16 + mrow) * 40 + kg * 8];
#pragma unroll
    for (int i = 0; i < 4; i++)
#pragma unroll
      for (int j = 0; j < 4; j++)
        acc[i][j] = __builtin_amdgcn_mfma_f32_16x16x32_bf16(af[i], bf[j], acc[i][j], 0, 0, 0);
  }
  // C/D layout: col = lane&15, row = (lane>>4)*4 + reg
#pragma unroll
  for (int i = 0; i < 4; i++)
#pragma unroll
    for (int j = 0; j < 4; j++)
#pragma unroll
      for (int r = 0; r < 4; r++) {
        int gr = m0 + wr * 64 + i * 16 + kg * 4 + r;
        int gc = n0 + wc * 64 + j * 16 + mrow;
        Cb[(size_t)gr * N + gc] = acc[i][j][r];
      }
}

// ---- 9-tap diagonal patch-sum * 1/norm ---------------------------------
// grid (9*L_, 1, G): bx%9 -> col block, bx/9 -> row
__global__ __launch_bounds__(256) void k_patchsum(const float* __restrict__ U,
                                                  float* __restrict__ V,
                                                  const float* __restrict__ ninv,
                                                  int b0) {
  int bx = blockIdx.x, bz = blockIdx.z;
  int col = (bx % 9) * 256 + threadIdx.x;
  int R = bx / 9;
  const float* Ub = U + (size_t)bz * L_ * L_;
  float* Vb = V + (size_t)bz * L_ * L_;
  int hq = R / h_, wq = R % h_, ps = col / h_, qs = col % h_;
  float s = 0.f;
#pragma unroll
  for (int a = 0; a < 3; a++) {
    int hi_ = hq - 1 + a, pi = ps - 1 + a;
    if ((unsigned)hi_ < (unsigned)h_ && (unsigned)pi < (unsigned)h_) {
#pragma unroll
      for (int bb = 0; bb < 3; bb++) {
        int wi = wq - 1 + bb, qi = qs - 1 + bb;
        if ((unsigned)wi < (unsigned)h_ && (unsigned)qi < (unsigned)h_)
          s += Ub[(size_t)(hi_ * h_ + wi) * L_ + pi * h_ + qi];
      }
    }
  }
  Vb[(size_t)R * L_ + col] = s * ninv[(size_t)(b0 + bz) * L_ + col];
}

// ---- fuse 1: flat L x L diagonal 3-tap ----------------------------------
__global__ __launch_bounds__(256) void k_fuse1(const float* __restrict__ In,
                                               float* __restrict__ Out) {
  int bx = blockIdx.x, bz = blockIdx.z;
  int col = (bx % 9) * 256 + threadIdx.x;
  int R = bx / 9;
  const float* Ib = In + (size_t)bz * L_ * L_;
  float s = 0.f;
#pragma unroll
  for (int d = -1; d <= 1; d++) {
    int r2 = R + d, c2 = col + d;
    if ((unsigned)r2 < (unsigned)L_ && (unsigned)c2 < (unsigned)L_)
      s += Ib[(size_t)r2 * L_ + c2];
  }
  Out[(size_t)bz * L_ * L_ + (size_t)R * L_ + col] = s;
}

// ---- fuse 2: diagonal 3-tap in transposed flattening --------------------
__global__ __launch_bounds__(256) void k_fuse2(const float* __restrict__ In,
                                               float* __restrict__ Out) {
  int bx = blockIdx.x, bz = blockIdx.z;
  int col = (bx % 9) * 256 + threadIdx.x;
  int R = bx / 9;
  const float* Ib = In + (size_t)bz * L_ * L_;
  int it = (R % h_) * h_ + R / h_;      // transposed flat index of row
  int jt = (col % h_) * h_ + col / h_;  // transposed flat index of col
  float s = 0.f;
#pragma unroll
  for (int d = -1; d <= 1; d++) {
    int i2 = it + d, j2 = jt + d;
    if ((unsigned)i2 < (unsigned)L_ && (unsigned)j2 < (unsigned)L_) {
      int r2 = (i2 % h_) * h_ + i2 / h_;
      int c2 = (j2 % h_) * h_ + j2 / h_;
      s += Ib[(size_t)r2 * L_ + c2];
    }
  }
  Out[(size_t)bz * L_ * L_ + (size_t)R * L_ + col] = s;
}

// ---- masked softmax over sources, emit bf16 attention -------------------
// grid (L_, G), one block per query row
__global__ __launch_bounds__(256) void k_softmax(const float* __restrict__ V,
                                                 const float* __restrict__ mm,
                                                 u16* __restrict__ Aout,
                                                 int b0) {
  int R = blockIdx.x, bz = blockIdx.y;
  const float* rowp = V + ((size_t)bz * L_ + R) * L_;
  const float* mmb = mm + (size_t)(b0 + bz) * L_;
  u16* arow = Aout + ((size_t)bz * L_ + R) * L_;
  int t = threadIdx.x;
  __shared__ float sred[256];
  float z[9];
  float mx = -3.0e38f;
#pragma unroll
  for (int i = 0; i < 9; i++) {
    int c = i * 256 + t;
    float zv = rowp[c] * mmb[c] * SCALE_;  // masked scores are exactly 0
    z[i] = zv;
    mx = fmaxf(mx, zv);
  }
  sred[t] = mx;
  __syncthreads();
  for (int s2 = 128; s2 > 0; s2 >>= 1) {
    if (t < s2) sred[t] = fmaxf(sred[t], sred[t + s2]);
    __syncthreads();
  }
  float MX = sred[0];
  __syncthreads();
  float sm = 0.f;
#pragma unroll
  for (int i = 0; i < 9; i++) {
    z[i] = __expf(z[i] - MX);
    sm += z[i];
  }
  sred[t] = sm;
  __syncthreads();
  for (int s2 = 128; s2 > 0; s2 >>= 1) {
    if (t < s2) sred[t] += sred[t + s2];
    __syncthreads();
  }
  float inv = 1.0f / sred[0];
#pragma unroll
  for (int i = 0; i < 9; i++) {
    int c = i * 256 + t;
    arow[c] = f2bf(z[i] * inv * mmb[c]);
  }
}

// ---- deconv parity-gather scatter ---------------------------------------
__global__ __launch_bounds__(256) void k_scatter(const float* __restrict__ P,
                                                 float* __restrict__ out) {
  int idx = blockIdx.x * 256 + threadIdx.x;
  int c = idx & 127;
  int r = idx >> 7;
  int xx = r % W_; r /= W_;
  int y = r % H_;
  int bz = r / H_;
  const float* Pb = P + (size_t)bz * L_ * N9_;
  int yo[2], ya[2], ny = 0;
  if (y & 1) { yo[0] = y >> 1; ya[0] = 1; ny = 1; }
  else {
    yo[0] = y >> 1; ya[0] = 0; ny = 1;
    if (y >= 2) { yo[1] = (y >> 1) - 1; ya[1] = 2; ny = 2; }
  }
  int xo[2], xa[2], nx = 0;
  if (xx & 1) { xo[0] = xx >> 1; xa[0] = 1; nx = 1; }
  else {
    xo[0] = xx >> 1; xa[0] = 0; nx = 1;
    if (xx >= 2) { xo[1] = (xx >> 1) - 1; xa[1] = 2; nx = 2; }
  }
  float s = 0.f;
  for (int i = 0; i < ny; i++)
    for (int j = 0; j < nx; j++)
      s += Pb[(size_t)(yo[i] * h_ + xo[j]) * N9_ + (ya[i] * 3 + xa[j]) * C_ + c];
  out[((size_t)bz * H_ + y) * (size_t)W_ * C_ + (size_t)xx * C_ + c] = 0.25f * s;
}

}  // namespace

extern "C" void kernel_launch(void* const* d_in, const int* in_sizes, int n_in,
                              void* d_out, int out_size, void* d_ws, size_t ws_size,
                              hipStream_t stream) {
  (void)in_sizes; (void)n_in; (void)out_size;
  const float* x = (const float*)d_in[0];
  const float* mask = (const float*)d_in[1];
  float* out = (float*)d_out;
  char* ws = (char*)d_ws;

  const size_t szF3 = (size_t)B_ * L_ * K3_ * sizeof(u16);
  const size_t szSm = (size_t)B_ * L_ * sizeof(float);
  const size_t off_F3a = 0;
  const size_t off_F3b = off_F3a + szF3;
  const size_t off_S = off_F3b + szF3;
  const size_t off_md = off_S + szSm;
  const size_t off_mm = off_md + szSm;
  const size_t off_nv = off_mm + szSm;
  const size_t off_fixed_end = off_nv + szSm;

  const size_t perXp = (size_t)N9_ * L_ * sizeof(u16);   // 5.3 MB / batch
  const size_t perUV = (size_t)L_ * L_ * sizeof(float);  // 21.2 MB / batch
  int G = 4;  // batches per super-batch; degrade if workspace is small
  while (G > 1 && off_fixed_end + (size_t)G * (perXp + 2 * perUV) > ws_size) G >>= 1;

  const size_t off_XpT = off_fixed_end;
  const size_t off_U = off_XpT + (size_t)G * perXp;
  const size_t off_V = off_U + (size_t)G * perUV;

  u16* F3a = (u16*)(ws + off_F3a);
  u16* F3b = (u16*)(ws + off_F3b);
  float* S = (float*)(ws + off_S);
  float* md = (float*)(ws + off_md);
  float* mm = (float*)(ws + off_mm);
  float* nv = (float*)(ws + off_nv);
  u16* XpT = (u16*)(ws + off_XpT);
  float* U = (float*)(ws + off_U);
  float* V = (float*)(ws + off_V);
  u16* Abuf = (u16*)(ws + off_U);                                   // alias lower half of U
  float* Pbuf = (float*)(ws + off_U + (size_t)G * L_ * L_ * sizeof(u16));  // alias upper half

  k_down<<<dim3(B_ * L_), dim3(C_), 0, stream>>>(x, F3a, F3b, S);
  k_mask<<<dim3((B_ * L_) / 256), dim3(256), 0, stream>>>(mask, md);
  k_mmnorm<<<dim3((B_ * L_) / 256), dim3(256), 0, stream>>>(S, md, mm, nv);

  for (int sb = 0; sb < B_; sb += G) {
    const float* xs = x + (size_t)sb * H_ * W_ * C_;
    k_xpack<<<dim3(L_ / 32, N9_ / 64, G), dim3(256), 0, stream>>>(xs, XpT);
    // Gram matrix (bf16x3 ~ fp32): U[i][j] = <f_i, f_j>
    gemm_bt<<<dim3(L_ / 128, L_ / 128, G), dim3(256), 0, stream>>>(
        F3a + (size_t)sb * L_ * K3_, F3b + (size_t)sb * L_ * K3_, U,
        L_, L_, K3_, (size_t)L_ * K3_, (size_t)L_ * K3_, (size_t)L_ * L_);
    k_patchsum<<<dim3(9 * L_, 1, G), dim3(256), 0, stream>>>(U, V, nv, sb);
    k_fuse1<<<dim3(9 * L_, 1, G), dim3(256), 0, stream>>>(V, U);
    k_fuse2<<<dim3(9 * L_, 1, G), dim3(256), 0, stream>>>(U, V);
    k_softmax<<<dim3(L_, G), dim3(256), 0, stream>>>(V, mm, Abuf, sb);
    // apply: P[hw][(a,b,c)] = sum_l A[hw][l] * XpT[(a,b,c)][l]
    gemm_bt<<<dim3(N9_ / 128, L_ / 128, G), dim3(256), 0, stream>>>(
        Abuf, XpT, Pbuf, L_, N9_, L_,
        (size_t)L_ * L_, (size_t)N9_ * L_, (size_t)L_ * N9_);
    k_scatter<<<dim3((G * H_ * W_ * C_) / 256), dim3(256), 0, stream>>>(
        Pbuf, out + (size_t)sb * H_ * W_ * C_);
  }
}

// Round 2
// 320.452 us; speedup vs baseline: 1.4516x; 1.4516x over previous
//
#include <hip/hip_runtime.h>
#include <stdint.h>
#include <string.h>

// ContextualAttention on MI355X.
// Pipeline:
//  k_down:    x -> (bf16x3 packed F3a/F3b for Gram GEMM) + per-pixel sumsq S
//  k_mask:    mask -> 2x2 avg-pooled md
//  k_mmnorm:  md,S -> mm (valid-patch mask), ninv (1/patch-norm)
//  k_xpack:   x -> XpT[j=(a,b,c)][l=(p,q)] bf16 (deconv weights, transposed for GEMM B)
//  gemm_bt:   U = F3a . F3b^T   (Gram matrix, fp32-accurate via bf16x3)
//  k_patchsum:V[hw][pq] = 9-tap diag stencil of U * ninv[pq]   (batched loads)
//  k_fsm:     fused fuse1 + fuse2 + masked softmax -> A (bf16)
//  gemm_bt:   P = A . XpT^T
//  k_scatter: out = parity-gather of P / 4

namespace {

constexpr int B_ = 4;
constexpr int H_ = 96;
constexpr int W_ = 96;
constexpr int C_ = 128;
constexpr int h_ = 48;
constexpr int L_ = 2304;   // h_*h_
constexpr int N9_ = 1152;  // 9*C_
constexpr int K3_ = 384;   // 3*C_  bf16x3 packed K
constexpr float SCALE_ = 10.0f;
constexpr float EPS_ = 1e-4f;

typedef unsigned short u16;
typedef __attribute__((ext_vector_type(8))) short bfrag8;   // 8 bf16 (4 VGPRs)
typedef __attribute__((ext_vector_type(4))) float f32x4;    // 4 fp32 acc

__device__ __forceinline__ u16 f2bf(float f) {
  uint32_t x;
  __builtin_memcpy(&x, &f, 4);
  uint32_t lsb = (x >> 16) & 1u;
  x += 0x7fffu + lsb;
  return (u16)(x >> 16);
}
__device__ __forceinline__ float bf2f(u16 u) {
  uint32_t v = ((uint32_t)u) << 16;
  float f;
  __builtin_memcpy(&f, &v, 4);
  return f;
}

// XCD-chunked bijective block swizzle (grid.x % 8 == 0 for all users)
__device__ __forceinline__ int xcd_swz(int bx, int nwg) {
  int chunk = nwg >> 3;
  return (bx & 7) * chunk + (bx >> 3);
}

// ---- downscale (2x2 avg) + bf16x3 pack + per-pixel sum of squares -------
__global__ __launch_bounds__(128) void k_down(const float* __restrict__ x,
                                              u16* __restrict__ F3a,
                                              u16* __restrict__ F3b,
                                              float* __restrict__ S) {
  int blk = blockIdx.x;
  int b = blk / L_, l = blk % L_;
  int p = l / h_, q = l % h_;
  int c = threadIdx.x;
  const float* xb = x + (((size_t)b * H_ + 2 * p) * W_ + 2 * q) * C_ + c;
  float v = 0.25f * (xb[0] + xb[C_] + xb[(size_t)W_ * C_] + xb[(size_t)W_ * C_ + C_]);
  u16 hi = f2bf(v);
  u16 lo = f2bf(v - bf2f(hi));
  size_t base = ((size_t)b * L_ + l) * K3_;
  F3a[base + c] = hi; F3a[base + 128 + c] = hi; F3a[base + 256 + c] = lo;
  F3b[base + c] = hi; F3b[base + 128 + c] = lo; F3b[base + 256 + c] = hi;
  __shared__ float red[128];
  red[c] = v * v;
  __syncthreads();
  for (int s2 = 64; s2 > 0; s2 >>= 1) {
    if (c < s2) red[c] += red[c + s2];
    __syncthreads();
  }
  if (c == 0) S[(size_t)b * L_ + l] = red[0];
}

// ---- mask 2x2 avg-pool --------------------------------------------------
__global__ __launch_bounds__(256) void k_mask(const float* __restrict__ mask,
                                              float* __restrict__ md) {
  int i = blockIdx.x * 256 + threadIdx.x;
  int b = i / L_, l = i % L_, p = l / h_, q = l % h_;
  const float* mb = mask + ((size_t)b * H_ + 2 * p) * W_ + 2 * q;
  md[i] = 0.25f * (mb[0] + mb[1] + mb[W_] + mb[W_ + 1]);
}

// ---- valid-patch mask + 1/patch-norm ------------------------------------
__global__ __launch_bounds__(256) void k_mmnorm(const float* __restrict__ S,
                                                const float* __restrict__ md,
                                                float* __restrict__ mm,
                                                float* __restrict__ ninv) {
  int i = blockIdx.x * 256 + threadIdx.x;
  int b = i / L_, l = i % L_, p = l / h_, q = l % h_;
  float ssum = 0.f, msum = 0.f;
#pragma unroll
  for (int a = 0; a < 3; a++) {
    int rp = p - 1 + a;
#pragma unroll
    for (int bb = 0; bb < 3; bb++) {
      int rq = q - 1 + bb;
      bool ok = ((unsigned)rp < (unsigned)h_) && ((unsigned)rq < (unsigned)h_);
      int idx = ok ? (b * L_ + rp * h_ + rq) : 0;
      float sv = S[idx], mv = md[idx];
      if (ok) { ssum += sv; msum += mv; }
    }
  }
  mm[i] = (msum == 0.f) ? 1.f : 0.f;
  float n = fmaxf(sqrtf(ssum), EPS_);
  ninv[i] = 1.f / n;
}

// ---- pack deconv weights transposed: XpT[bz][j=(a,bb,c)][l=(p,q)] -------
__global__ __launch_bounds__(256) void k_xpack(const float* __restrict__ x,
                                               u16* __restrict__ XpT) {
  int lt = blockIdx.x * 32, jt = blockIdx.y * 64, bz = blockIdx.z;
  __shared__ u16 tile[32][65];
  int t = threadIdx.x;
  int jj = t & 63, lq = t >> 6;
  for (int pass = 0; pass < 8; ++pass) {
    int ll = pass * 4 + lq;
    int l = lt + ll;
    int p = l / h_, q = l % h_;
    int j = jt + jj;
    int a = j / 384, rem = j % 384, bb = rem / 128, c = rem % 128;
    int gy = 2 * p + a, gx = 2 * q + bb;
    float v = 0.f;
    if (gy < H_ && gx < W_) v = x[(((size_t)bz * H_ + gy) * W_ + gx) * C_ + c];
    tile[ll][jj] = f2bf(v);
  }
  __syncthreads();
  int lw = t & 31, jq = t >> 5;
  for (int pass = 0; pass < 8; ++pass) {
    int j2 = pass * 8 + jq;
    XpT[((size_t)bz * N9_ + jt + j2) * L_ + lt + lw] = tile[lw][j2];
  }
}

// ---- MFMA GEMM: C[m][n] = sum_k A[m][k]*B[n][k] -------------------------
__global__ __launch_bounds__(256) void gemm_bt(const u16* __restrict__ A,
                                               const u16* __restrict__ B,
                                               float* __restrict__ C,
                                               int M, int N, int Kd,
                                               size_t sA, size_t sB, size_t sC) {
  const u16* Ab = A + (size_t)blockIdx.z * sA;
  const u16* Bb = B + (size_t)blockIdx.z * sB;
  float* Cb = C + (size_t)blockIdx.z * sC;
  int m0 = blockIdx.y * 128, n0 = blockIdx.x * 128;
  __shared__ u16 As[128 * 40];
  __shared__ u16 Bs[128 * 40];
  int t = threadIdx.x;
  int lane = t & 63, wv = t >> 6, wr = wv >> 1, wc = wv & 1;
  int mrow = lane & 15, kg = lane >> 4;
  f32x4 acc[4][4];
#pragma unroll
  for (int i = 0; i < 4; i++)
#pragma unroll
    for (int j = 0; j < 4; j++) acc[i][j] = (f32x4)(0.0f);

  int row = t >> 2, kc = t & 3;
  for (int k0 = 0; k0 < Kd; k0 += 32) {
    bfrag8 av0 = *(const bfrag8*)(Ab + (size_t)(m0 + row) * Kd + k0 + kc * 8);
    bfrag8 av1 = *(const bfrag8*)(Ab + (size_t)(m0 + 64 + row) * Kd + k0 + kc * 8);
    bfrag8 bv0 = *(const bfrag8*)(Bb + (size_t)(n0 + row) * Kd + k0 + kc * 8);
    bfrag8 bv1 = *(const bfrag8*)(Bb + (size_t)(n0 + 64 + row) * Kd + k0 + kc * 8);
    __syncthreads();
    *(bfrag8*)&As[(row)*40 + kc * 8] = av0;
    *(bfrag8*)&As[(row + 64) * 40 + kc * 8] = av1;
    *(bfrag8*)&Bs[(row)*40 + kc * 8] = bv0;
    *(bfrag8*)&Bs[(row + 64) * 40 + kc * 8] = bv1;
    __syncthreads();
    bfrag8 af[4], bf[4];
#pragma unroll
    for (int i = 0; i < 4; i++)
      af[i] = *(const bfrag8*)&As[(wr * 64 + i * 16 + mrow) * 40 + kg * 8];
#pragma unroll
    for (int i = 0; i < 4; i++)
      bf[i] = *(const bfrag8*)&Bs[(wc * 64 + i * 16 + mrow) * 40 + kg * 8];
#pragma unroll
    for (int i = 0; i < 4; i++)
#pragma unroll
      for (int j = 0; j < 4; j++)
        acc[i][j] = __builtin_amdgcn_mfma_f32_16x16x32_bf16(af[i], bf[j], acc[i][j], 0, 0, 0);
  }
#pragma unroll
  for (int i = 0; i < 4; i++)
#pragma unroll
    for (int j = 0; j < 4; j++)
#pragma unroll
      for (int r = 0; r < 4; r++) {
        int gr = m0 + wr * 64 + i * 16 + kg * 4 + r;
        int gc = n0 + wc * 64 + j * 16 + mrow;
        Cb[(size_t)gr * N + gc] = acc[i][j][r];
      }
}

// ---- 9-tap diagonal patch-sum * 1/norm (batched unconditional loads) ----
__global__ __launch_bounds__(256) void k_patchsum(const float* __restrict__ U,
                                                  float* __restrict__ V,
                                                  const float* __restrict__ ninv,
                                                  int b0) {
  int bx = xcd_swz(blockIdx.x, 9 * L_), bz = blockIdx.z;
  int col = (bx % 9) * 256 + threadIdx.x;
  int R = bx / 9;
  const float* Ub = U + (size_t)bz * L_ * L_;
  float* Vb = V + (size_t)bz * L_ * L_;
  int hq = R / h_, wq = R % h_, ps = col / h_, qs = col % h_;
  float v[9], w[9];
#pragma unroll
  for (int a = 0; a < 3; a++) {
#pragma unroll
    for (int bb = 0; bb < 3; bb++) {
      int k = a * 3 + bb;
      int iy = hq - 1 + a, ix = wq - 1 + bb;
      int jy = ps - 1 + a, jx = qs - 1 + bb;
      bool ok = ((unsigned)iy < (unsigned)h_) & ((unsigned)ix < (unsigned)h_) &
                ((unsigned)jy < (unsigned)h_) & ((unsigned)jx < (unsigned)h_);
      size_t ad = ok ? ((size_t)(iy * h_ + ix) * L_ + (jy * h_ + jx)) : 0;
      v[k] = Ub[ad];
      w[k] = ok ? 1.f : 0.f;
    }
  }
  float s = 0.f;
#pragma unroll
  for (int k = 0; k < 9; k++) s += v[k] * w[k];
  Vb[(size_t)R * L_ + col] = s * ninv[(size_t)(b0 + bz) * L_ + col];
}

// ---- fused fuse1 + fuse2 + masked softmax -> bf16 attention -------------
// Y[i][j] = sum_{d2,d1} V1[T(T(i)+d2)+d1][T(T(j)+d2)+d1], joint flat clamps.
// One block per query row i; 256 threads x 9 cols.
__global__ __launch_bounds__(256) void k_fsm(const float* __restrict__ V1,
                                             const float* __restrict__ mm,
                                             u16* __restrict__ Aout,
                                             int b0) {
  int i = xcd_swz(blockIdx.x, L_), bz = blockIdx.y;
  int hq = i / h_, wq = i % h_;
  const float* Vb = V1 + (size_t)bz * L_ * L_;
  const float* mmb = mm + (size_t)(b0 + bz) * L_;
  u16* arow = Aout + ((size_t)bz * L_ + i) * L_;
  int t = threadIdx.x;

  int iB[3]; bool rOK[3];
#pragma unroll
  for (int d2 = 0; d2 < 3; d2++) {
    int TA = wq * h_ + hq + (d2 - 1);
    bool ok = (TA >= 0) && (TA < L_);
    rOK[d2] = ok;
    int TAc = ok ? TA : 0;
    iB[d2] = (TAc % h_) * h_ + TAc / h_;
  }

  __shared__ float sred[256];
  float y[9];
  float mx = -3.0e38f;
#pragma unroll
  for (int cc = 0; cc < 9; cc++) {
    int j = cc * 256 + t;
    int jy = j / h_, jx = j % h_;
    float v[9], w[9];
#pragma unroll
    for (int d2 = 0; d2 < 3; d2++) {
      int TB = jx * h_ + jy + (d2 - 1);
      bool cOK = rOK[d2] && (TB >= 0) && (TB < L_);
      int TBc = cOK ? TB : 0;
      int jB = (TBc % h_) * h_ + TBc / h_;
#pragma unroll
      for (int d1 = 0; d1 < 3; d1++) {
        int k = d2 * 3 + d1;
        int iG = iB[d2] + (d1 - 1), jG = jB + (d1 - 1);
        bool ok = cOK && ((unsigned)iG < (unsigned)L_) && ((unsigned)jG < (unsigned)L_);
        size_t ad = ok ? ((size_t)iG * L_ + jG) : 0;
        v[k] = Vb[ad];
        w[k] = ok ? 1.f : 0.f;
      }
    }
    float s = 0.f;
#pragma unroll
    for (int k = 0; k < 9; k++) s += v[k] * w[k];
    float zv = s * mmb[j] * SCALE_;
    y[cc] = zv;
    mx = fmaxf(mx, zv);
  }
  sred[t] = mx;
  __syncthreads();
  for (int s2 = 128; s2 > 0; s2 >>= 1) {
    if (t < s2) sred[t] = fmaxf(sred[t], sred[t + s2]);
    __syncthreads();
  }
  float MX = sred[0];
  __syncthreads();
  float sm = 0.f;
#pragma unroll
  for (int cc = 0; cc < 9; cc++) {
    y[cc] = __expf(y[cc] - MX);
    sm += y[cc];
  }
  sred[t] = sm;
  __syncthreads();
  for (int s2 = 128; s2 > 0; s2 >>= 1) {
    if (t < s2) sred[t] += sred[t + s2];
    __syncthreads();
  }
  float inv = 1.0f / sred[0];
#pragma unroll
  for (int cc = 0; cc < 9; cc++) {
    int j = cc * 256 + t;
    arow[j] = f2bf(y[cc] * inv * mmb[j]);
  }
}

// ---- deconv parity-gather scatter ---------------------------------------
__global__ __launch_bounds__(256) void k_scatter(const float* __restrict__ P,
                                                 float* __restrict__ out) {
  int idx = blockIdx.x * 256 + threadIdx.x;
  int c = idx & 127;
  int r = idx >> 7;
  int xx = r % W_; r /= W_;
  int y = r % H_;
  int bz = r / H_;
  const float* Pb = P + (size_t)bz * L_ * N9_;
  int yo[2], ya[2], ny = 0;
  if (y & 1) { yo[0] = y >> 1; ya[0] = 1; ny = 1; }
  else {
    yo[0] = y >> 1; ya[0] = 0; ny = 1;
    if (y >= 2) { yo[1] = (y >> 1) - 1; ya[1] = 2; ny = 2; }
  }
  int xo[2], xa[2], nx = 0;
  if (xx & 1) { xo[0] = xx >> 1; xa[0] = 1; nx = 1; }
  else {
    xo[0] = xx >> 1; xa[0] = 0; nx = 1;
    if (xx >= 2) { xo[1] = (xx >> 1) - 1; xa[1] = 2; nx = 2; }
  }
  float s = 0.f;
  for (int i = 0; i < ny; i++)
    for (int j = 0; j < nx; j++)
      s += Pb[(size_t)(yo[i] * h_ + xo[j]) * N9_ + (ya[i] * 3 + xa[j]) * C_ + c];
  out[((size_t)bz * H_ + y) * (size_t)W_ * C_ + (size_t)xx * C_ + c] = 0.25f * s;
}

}  // namespace

extern "C" void kernel_launch(void* const* d_in, const int* in_sizes, int n_in,
                              void* d_out, int out_size, void* d_ws, size_t ws_size,
                              hipStream_t stream) {
  (void)in_sizes; (void)n_in; (void)out_size;
  const float* x = (const float*)d_in[0];
  const float* mask = (const float*)d_in[1];
  float* out = (float*)d_out;
  char* ws = (char*)d_ws;

  const size_t szF3 = (size_t)B_ * L_ * K3_ * sizeof(u16);
  const size_t szSm = (size_t)B_ * L_ * sizeof(float);
  const size_t off_F3a = 0;
  const size_t off_F3b = off_F3a + szF3;
  const size_t off_S = off_F3b + szF3;
  const size_t off_md = off_S + szSm;
  const size_t off_mm = off_md + szSm;
  const size_t off_nv = off_mm + szSm;
  const size_t off_fixed_end = off_nv + szSm;

  const size_t perXp = (size_t)N9_ * L_ * sizeof(u16);
  const size_t perUV = (size_t)L_ * L_ * sizeof(float);
  int G = 4;
  while (G > 1 && off_fixed_end + (size_t)G * (perXp + 2 * perUV) > ws_size) G >>= 1;

  const size_t off_XpT = off_fixed_end;
  const size_t off_U = off_XpT + (size_t)G * perXp;
  const size_t off_V = off_U + (size_t)G * perUV;

  u16* F3a = (u16*)(ws + off_F3a);
  u16* F3b = (u16*)(ws + off_F3b);
  float* S = (float*)(ws + off_S);
  float* md = (float*)(ws + off_md);
  float* mm = (float*)(ws + off_mm);
  float* nv = (float*)(ws + off_nv);
  u16* XpT = (u16*)(ws + off_XpT);
  float* U = (float*)(ws + off_U);
  float* V = (float*)(ws + off_V);
  u16* Abuf = (u16*)(ws + off_U);
  float* Pbuf = (float*)(ws + off_U + (size_t)G * L_ * L_ * sizeof(u16));

  k_down<<<dim3(B_ * L_), dim3(C_), 0, stream>>>(x, F3a, F3b, S);
  k_mask<<<dim3((B_ * L_) / 256), dim3(256), 0, stream>>>(mask, md);
  k_mmnorm<<<dim3((B_ * L_) / 256), dim3(256), 0, stream>>>(S, md, mm, nv);

  for (int sb = 0; sb < B_; sb += G) {
    const float* xs = x + (size_t)sb * H_ * W_ * C_;
    k_xpack<<<dim3(L_ / 32, N9_ / 64, G), dim3(256), 0, stream>>>(xs, XpT);
    gemm_bt<<<dim3(L_ / 128, L_ / 128, G), dim3(256), 0, stream>>>(
        F3a + (size_t)sb * L_ * K3_, F3b + (size_t)sb * L_ * K3_, U,
        L_, L_, K3_, (size_t)L_ * K3_, (size_t)L_ * K3_, (size_t)L_ * L_);
    k_patchsum<<<dim3(9 * L_, 1, G), dim3(256), 0, stream>>>(U, V, nv, sb);
    k_fsm<<<dim3(L_, G), dim3(256), 0, stream>>>(V, mm, Abuf, sb);
    gemm_bt<<<dim3(N9_ / 128, L_ / 128, G), dim3(256), 0, stream>>>(
        Abuf, XpT, Pbuf, L_, N9_, L_,
        (size_t)L_ * L_, (size_t)N9_ * L_, (size_t)L_ * N9_);
    k_scatter<<<dim3((G * H_ * W_ * C_) / 256), dim3(256), 0, stream>>>(
        Pbuf, out + (size_t)sb * H_ * W_ * C_);
  }
}

// Round 3
// 289.096 us; speedup vs baseline: 1.6091x; 1.1085x over previous
//
#include <hip/hip_runtime.h>
#include <stdint.h>
#include <string.h>

// ContextualAttention on MI355X.
// Pipeline:
//  k_down:    x -> (bf16x3 packed F3a/F3b for Gram GEMM) + per-pixel sumsq S
//  k_mask:    mask -> 2x2 avg-pooled md
//  k_mmnorm:  md,S -> mm (valid-patch mask), ninv (1/patch-norm)
//  k_xpack:   x -> XpT[j=(a,b,c)][l=(p,q)] bf16 (deconv weights, transposed for GEMM B)
//  gemm_bt<false>: U = F3a . F3b^T   (Gram matrix, fp32-accurate via bf16x3)
//  k_patchsum:V[hw][pq] = 9-tap diag stencil of U * ninv[pq]
//  k_fsm:     fused fuse1 + fuse2 + masked softmax -> A (bf16)
//  gemm_bt<true>:  P(bf16) = A . XpT^T
//  k_scatter: out = parity-gather of P / 4

namespace {

constexpr int B_ = 4;
constexpr int H_ = 96;
constexpr int W_ = 96;
constexpr int C_ = 128;
constexpr int h_ = 48;
constexpr int L_ = 2304;   // h_*h_
constexpr int N9_ = 1152;  // 9*C_
constexpr int K3_ = 384;   // 3*C_  bf16x3 packed K
constexpr float SCALE_ = 10.0f;
constexpr float EPS_ = 1e-4f;

typedef unsigned short u16;
typedef __attribute__((ext_vector_type(8))) short bfrag8;   // 8 bf16 (4 VGPRs)
typedef __attribute__((ext_vector_type(4))) float f32x4;    // 4 fp32 acc

__device__ __forceinline__ u16 f2bf(float f) {
  uint32_t x;
  __builtin_memcpy(&x, &f, 4);
  uint32_t lsb = (x >> 16) & 1u;
  x += 0x7fffu + lsb;
  return (u16)(x >> 16);
}
__device__ __forceinline__ float bf2f(u16 u) {
  uint32_t v = ((uint32_t)u) << 16;
  float f;
  __builtin_memcpy(&f, &v, 4);
  return f;
}

// async global(16B/lane) -> LDS (wave-uniform base + lane*16)
__device__ __forceinline__ void gload16(const u16* g, u16* l) {
  __builtin_amdgcn_global_load_lds(
      (const __attribute__((address_space(1))) void*)g,
      (__attribute__((address_space(3))) void*)l, 16, 0, 0);
}

// XCD-chunked bijective block swizzle (m204 variant, any nwg)
__device__ __forceinline__ int xcd_swz8(int orig, int nwg) {
  int q = nwg >> 3, r = nwg & 7;
  int xcd = orig & 7, pos = orig >> 3;
  return (xcd < r ? xcd * (q + 1) : r * (q + 1) + (xcd - r) * q) + pos;
}

// ---- downscale (2x2 avg) + bf16x3 pack + per-pixel sum of squares -------
__global__ __launch_bounds__(128) void k_down(const float* __restrict__ x,
                                              u16* __restrict__ F3a,
                                              u16* __restrict__ F3b,
                                              float* __restrict__ S) {
  int blk = blockIdx.x;
  int b = blk / L_, l = blk % L_;
  int p = l / h_, q = l % h_;
  int c = threadIdx.x;
  const float* xb = x + (((size_t)b * H_ + 2 * p) * W_ + 2 * q) * C_ + c;
  float v = 0.25f * (xb[0] + xb[C_] + xb[(size_t)W_ * C_] + xb[(size_t)W_ * C_ + C_]);
  u16 hi = f2bf(v);
  u16 lo = f2bf(v - bf2f(hi));
  size_t base = ((size_t)b * L_ + l) * K3_;
  F3a[base + c] = hi; F3a[base + 128 + c] = hi; F3a[base + 256 + c] = lo;
  F3b[base + c] = hi; F3b[base + 128 + c] = lo; F3b[base + 256 + c] = hi;
  __shared__ float red[128];
  red[c] = v * v;
  __syncthreads();
  for (int s2 = 64; s2 > 0; s2 >>= 1) {
    if (c < s2) red[c] += red[c + s2];
    __syncthreads();
  }
  if (c == 0) S[(size_t)b * L_ + l] = red[0];
}

// ---- mask 2x2 avg-pool --------------------------------------------------
__global__ __launch_bounds__(256) void k_mask(const float* __restrict__ mask,
                                              float* __restrict__ md) {
  int i = blockIdx.x * 256 + threadIdx.x;
  int b = i / L_, l = i % L_, p = l / h_, q = l % h_;
  const float* mb = mask + ((size_t)b * H_ + 2 * p) * W_ + 2 * q;
  md[i] = 0.25f * (mb[0] + mb[1] + mb[W_] + mb[W_ + 1]);
}

// ---- valid-patch mask + 1/patch-norm ------------------------------------
__global__ __launch_bounds__(256) void k_mmnorm(const float* __restrict__ S,
                                                const float* __restrict__ md,
                                                float* __restrict__ mm,
                                                float* __restrict__ ninv) {
  int i = blockIdx.x * 256 + threadIdx.x;
  int b = i / L_, l = i % L_, p = l / h_, q = l % h_;
  float ssum = 0.f, msum = 0.f;
#pragma unroll
  for (int a = 0; a < 3; a++) {
    int rp = p - 1 + a;
#pragma unroll
    for (int bb = 0; bb < 3; bb++) {
      int rq = q - 1 + bb;
      bool ok = ((unsigned)rp < (unsigned)h_) && ((unsigned)rq < (unsigned)h_);
      int idx = ok ? (b * L_ + rp * h_ + rq) : 0;
      float sv = S[idx], mv = md[idx];
      if (ok) { ssum += sv; msum += mv; }
    }
  }
  mm[i] = (msum == 0.f) ? 1.f : 0.f;
  float n = fmaxf(sqrtf(ssum), EPS_);
  ninv[i] = 1.f / n;
}

// ---- pack deconv weights transposed: XpT[bz][j=(a,bb,c)][l=(p,q)] -------
__global__ __launch_bounds__(256) void k_xpack(const float* __restrict__ x,
                                               u16* __restrict__ XpT) {
  int lt = blockIdx.x * 32, jt = blockIdx.y * 64, bz = blockIdx.z;
  __shared__ u16 tile[32][65];
  int t = threadIdx.x;
  int jj = t & 63, lq = t >> 6;
  for (int pass = 0; pass < 8; ++pass) {
    int ll = pass * 4 + lq;
    int l = lt + ll;
    int p = l / h_, q = l % h_;
    int j = jt + jj;
    int a = j / 384, rem = j % 384, bb = rem / 128, c = rem % 128;
    int gy = 2 * p + a, gx = 2 * q + bb;
    float v = 0.f;
    if (gy < H_ && gx < W_) v = x[(((size_t)bz * H_ + gy) * W_ + gx) * C_ + c];
    tile[ll][jj] = f2bf(v);
  }
  __syncthreads();
  int lw = t & 31, jq = t >> 5;
  for (int pass = 0; pass < 8; ++pass) {
    int j2 = pass * 8 + jq;
    XpT[((size_t)bz * N9_ + jt + j2) * L_ + lt + lw] = tile[lw][j2];
  }
}

// ---- MFMA GEMM (m97 structure): C[m][n] = sum_k A[m][k]*B[n][k] ---------
// 128x128 tile, 4 waves (2x2), BK=32, global_load_lds width-16 staging,
// linear LDS [128][32], XCD-swizzled grid (n-major within chunk).
template <bool OUTBF>
__global__ __launch_bounds__(256) void gemm_bt(const u16* __restrict__ A,
                                               const u16* __restrict__ B,
                                               void* __restrict__ Cv,
                                               int N, int Kd,
                                               size_t sA, size_t sB, size_t sC) {
  const u16* Ab = A + (size_t)blockIdx.z * sA;
  const u16* Bb = B + (size_t)blockIdx.z * sB;
  int nwg = gridDim.x * gridDim.y;
  int orig = blockIdx.y * gridDim.x + blockIdx.x;   // n-minor linearization
  int wgid = xcd_swz8(orig, nwg);
  int bx = wgid % gridDim.x, by = wgid / gridDim.x;
  int m0 = by * 128, n0 = bx * 128;

  __shared__ u16 As[128 * 32];
  __shared__ u16 Bs[128 * 32];
  int t = threadIdx.x;
  int lane = t & 63, wv = t >> 6, wr = wv >> 1, wc = wv & 1;
  int mrow = lane & 15, kg = lane >> 4;
  f32x4 acc[4][4];
#pragma unroll
  for (int i = 0; i < 4; i++)
#pragma unroll
    for (int j = 0; j < 4; j++) acc[i][j] = (f32x4)(0.0f);

  int row = t >> 2, kc = t & 3;  // staging: thread -> (row, 16B chunk), flat byte = t*16
  const u16* ga0 = Ab + (size_t)(m0 + row) * Kd + kc * 8;
  const u16* ga1 = ga0 + (size_t)64 * Kd;
  const u16* gb0 = Bb + (size_t)(n0 + row) * Kd + kc * 8;
  const u16* gb1 = gb0 + (size_t)64 * Kd;
  u16* lA0 = As + wv * 512;          // wave-uniform LDS bases (bytes: wv*1024)
  u16* lA1 = As + 2048 + wv * 512;
  u16* lB0 = Bs + wv * 512;
  u16* lB1 = Bs + 2048 + wv * 512;

  for (int k0 = 0; k0 < Kd; k0 += 32) {
    __syncthreads();               // all waves done reading previous tile
    gload16(ga0 + k0, lA0);
    gload16(ga1 + k0, lA1);
    gload16(gb0 + k0, lB0);
    gload16(gb1 + k0, lB1);
    __syncthreads();               // compiler drains vmcnt before barrier -> tile ready
    bfrag8 af[4], bf[4];
#pragma unroll
    for (int i = 0; i < 4; i++)
      af[i] = *(const bfrag8*)&As[(wr * 64 + i * 16 + mrow) * 32 + kg * 8];
#pragma unroll
    for (int i = 0; i < 4; i++)
      bf[i] = *(const bfrag8*)&Bs[(wc * 64 + i * 16 + mrow) * 32 + kg * 8];
#pragma unroll
    for (int i = 0; i < 4; i++)
#pragma unroll
      for (int j = 0; j < 4; j++)
        acc[i][j] = __builtin_amdgcn_mfma_f32_16x16x32_bf16(af[i], bf[j], acc[i][j], 0, 0, 0);
  }
  // C/D layout: col = lane&15, row = (lane>>4)*4 + reg
#pragma unroll
  for (int i = 0; i < 4; i++)
#pragma unroll
    for (int j = 0; j < 4; j++)
#pragma unroll
      for (int r = 0; r < 4; r++) {
        int gr = m0 + wr * 64 + i * 16 + kg * 4 + r;
        int gc = n0 + wc * 64 + j * 16 + mrow;
        if (OUTBF) {
          ((u16*)Cv)[(size_t)blockIdx.z * sC + (size_t)gr * N + gc] = f2bf(acc[i][j][r]);
        } else {
          ((float*)Cv)[(size_t)blockIdx.z * sC + (size_t)gr * N + gc] = acc[i][j][r];
        }
      }
}

// ---- 9-tap diagonal patch-sum * 1/norm (batched unconditional loads) ----
__global__ __launch_bounds__(256) void k_patchsum(const float* __restrict__ U,
                                                  float* __restrict__ V,
                                                  const float* __restrict__ ninv,
                                                  int b0) {
  int bx = xcd_swz8(blockIdx.x, 9 * L_), bz = blockIdx.z;
  int col = (bx % 9) * 256 + threadIdx.x;
  int R = bx / 9;
  const float* Ub = U + (size_t)bz * L_ * L_;
  float* Vb = V + (size_t)bz * L_ * L_;
  int hq = R / h_, wq = R % h_, ps = col / h_, qs = col % h_;
  float v[9], w[9];
#pragma unroll
  for (int a = 0; a < 3; a++) {
#pragma unroll
    for (int bb = 0; bb < 3; bb++) {
      int k = a * 3 + bb;
      int iy = hq - 1 + a, ix = wq - 1 + bb;
      int jy = ps - 1 + a, jx = qs - 1 + bb;
      bool ok = ((unsigned)iy < (unsigned)h_) & ((unsigned)ix < (unsigned)h_) &
                ((unsigned)jy < (unsigned)h_) & ((unsigned)jx < (unsigned)h_);
      size_t ad = ok ? ((size_t)(iy * h_ + ix) * L_ + (jy * h_ + jx)) : 0;
      v[k] = Ub[ad];
      w[k] = ok ? 1.f : 0.f;
    }
  }
  float s = 0.f;
#pragma unroll
  for (int k = 0; k < 9; k++) s += v[k] * w[k];
  Vb[(size_t)R * L_ + col] = s * ninv[(size_t)(b0 + bz) * L_ + col];
}

// ---- fused fuse1 + fuse2 + masked softmax -> bf16 attention -------------
__global__ __launch_bounds__(256) void k_fsm(const float* __restrict__ V1,
                                             const float* __restrict__ mm,
                                             u16* __restrict__ Aout,
                                             int b0) {
  int i = xcd_swz8(blockIdx.x, L_), bz = blockIdx.y;
  int hq = i / h_, wq = i % h_;
  const float* Vb = V1 + (size_t)bz * L_ * L_;
  const float* mmb = mm + (size_t)(b0 + bz) * L_;
  u16* arow = Aout + ((size_t)bz * L_ + i) * L_;
  int t = threadIdx.x;

  int iB[3]; bool rOK[3];
#pragma unroll
  for (int d2 = 0; d2 < 3; d2++) {
    int TA = wq * h_ + hq + (d2 - 1);
    bool ok = (TA >= 0) && (TA < L_);
    rOK[d2] = ok;
    int TAc = ok ? TA : 0;
    iB[d2] = (TAc % h_) * h_ + TAc / h_;
  }

  __shared__ float sred[256];
  float y[9];
  float mx = -3.0e38f;
#pragma unroll
  for (int cc = 0; cc < 9; cc++) {
    int j = cc * 256 + t;
    int jy = j / h_, jx = j % h_;
    float v[9], w[9];
#pragma unroll
    for (int d2 = 0; d2 < 3; d2++) {
      int TB = jx * h_ + jy + (d2 - 1);
      bool cOK = rOK[d2] && (TB >= 0) && (TB < L_);
      int TBc = cOK ? TB : 0;
      int jB = (TBc % h_) * h_ + TBc / h_;
#pragma unroll
      for (int d1 = 0; d1 < 3; d1++) {
        int k = d2 * 3 + d1;
        int iG = iB[d2] + (d1 - 1), jG = jB + (d1 - 1);
        bool ok = cOK && ((unsigned)iG < (unsigned)L_) && ((unsigned)jG < (unsigned)L_);
        size_t ad = ok ? ((size_t)iG * L_ + jG) : 0;
        v[k] = Vb[ad];
        w[k] = ok ? 1.f : 0.f;
      }
    }
    float s = 0.f;
#pragma unroll
    for (int k = 0; k < 9; k++) s += v[k] * w[k];
    float zv = s * mmb[j] * SCALE_;
    y[cc] = zv;
    mx = fmaxf(mx, zv);
  }
  sred[t] = mx;
  __syncthreads();
  for (int s2 = 128; s2 > 0; s2 >>= 1) {
    if (t < s2) sred[t] = fmaxf(sred[t], sred[t + s2]);
    __syncthreads();
  }
  float MX = sred[0];
  __syncthreads();
  float sm = 0.f;
#pragma unroll
  for (int cc = 0; cc < 9; cc++) {
    y[cc] = __expf(y[cc] - MX);
    sm += y[cc];
  }
  sred[t] = sm;
  __syncthreads();
  for (int s2 = 128; s2 > 0; s2 >>= 1) {
    if (t < s2) sred[t] += sred[t + s2];
    __syncthreads();
  }
  float inv = 1.0f / sred[0];
#pragma unroll
  for (int cc = 0; cc < 9; cc++) {
    int j = cc * 256 + t;
    arow[j] = f2bf(y[cc] * inv * mmb[j]);
  }
}

// ---- deconv parity-gather scatter (P is bf16) ---------------------------
__global__ __launch_bounds__(256) void k_scatter(const u16* __restrict__ P,
                                                 float* __restrict__ out) {
  int idx = blockIdx.x * 256 + threadIdx.x;
  int c = idx & 127;
  int r = idx >> 7;
  int xx = r % W_; r /= W_;
  int y = r % H_;
  int bz = r / H_;
  const u16* Pb = P + (size_t)bz * L_ * N9_;
  int yo[2], ya[2], ny = 0;
  if (y & 1) { yo[0] = y >> 1; ya[0] = 1; ny = 1; }
  else {
    yo[0] = y >> 1; ya[0] = 0; ny = 1;
    if (y >= 2) { yo[1] = (y >> 1) - 1; ya[1] = 2; ny = 2; }
  }
  int xo[2], xa[2], nx = 0;
  if (xx & 1) { xo[0] = xx >> 1; xa[0] = 1; nx = 1; }
  else {
    xo[0] = xx >> 1; xa[0] = 0; nx = 1;
    if (xx >= 2) { xo[1] = (xx >> 1) - 1; xa[1] = 2; nx = 2; }
  }
  float s = 0.f;
  for (int i = 0; i < ny; i++)
    for (int j = 0; j < nx; j++)
      s += bf2f(Pb[(size_t)(yo[i] * h_ + xo[j]) * N9_ + (ya[i] * 3 + xa[j]) * C_ + c]);
  out[((size_t)bz * H_ + y) * (size_t)W_ * C_ + (size_t)xx * C_ + c] = 0.25f * s;
}

}  // namespace

extern "C" void kernel_launch(void* const* d_in, const int* in_sizes, int n_in,
                              void* d_out, int out_size, void* d_ws, size_t ws_size,
                              hipStream_t stream) {
  (void)in_sizes; (void)n_in; (void)out_size;
  const float* x = (const float*)d_in[0];
  const float* mask = (const float*)d_in[1];
  float* out = (float*)d_out;
  char* ws = (char*)d_ws;

  const size_t szF3 = (size_t)B_ * L_ * K3_ * sizeof(u16);
  const size_t szSm = (size_t)B_ * L_ * sizeof(float);
  const size_t off_F3a = 0;
  const size_t off_F3b = off_F3a + szF3;
  const size_t off_S = off_F3b + szF3;
  const size_t off_md = off_S + szSm;
  const size_t off_mm = off_md + szSm;
  const size_t off_nv = off_mm + szSm;
  const size_t off_fixed_end = off_nv + szSm;

  const size_t perXp = (size_t)N9_ * L_ * sizeof(u16);
  const size_t perUV = (size_t)L_ * L_ * sizeof(float);
  int G = 4;
  while (G > 1 && off_fixed_end + (size_t)G * (perXp + 2 * perUV) > ws_size) G >>= 1;

  const size_t off_XpT = off_fixed_end;
  const size_t off_U = off_XpT + (size_t)G * perXp;
  const size_t off_V = off_U + (size_t)G * perUV;

  u16* F3a = (u16*)(ws + off_F3a);
  u16* F3b = (u16*)(ws + off_F3b);
  float* S = (float*)(ws + off_S);
  float* md = (float*)(ws + off_md);
  float* mm = (float*)(ws + off_mm);
  float* nv = (float*)(ws + off_nv);
  u16* XpT = (u16*)(ws + off_XpT);
  float* U = (float*)(ws + off_U);
  float* V = (float*)(ws + off_V);
  u16* Abuf = (u16*)(ws + off_U);                                      // alias U lower half
  u16* Pbuf = (u16*)(ws + off_U + (size_t)G * L_ * L_ * sizeof(u16));  // alias after A

  k_down<<<dim3(B_ * L_), dim3(C_), 0, stream>>>(x, F3a, F3b, S);
  k_mask<<<dim3((B_ * L_) / 256), dim3(256), 0, stream>>>(mask, md);
  k_mmnorm<<<dim3((B_ * L_) / 256), dim3(256), 0, stream>>>(S, md, mm, nv);

  for (int sb = 0; sb < B_; sb += G) {
    const float* xs = x + (size_t)sb * H_ * W_ * C_;
    k_xpack<<<dim3(L_ / 32, N9_ / 64, G), dim3(256), 0, stream>>>(xs, XpT);
    gemm_bt<false><<<dim3(L_ / 128, L_ / 128, G), dim3(256), 0, stream>>>(
        F3a + (size_t)sb * L_ * K3_, F3b + (size_t)sb * L_ * K3_, (void*)U,
        L_, K3_, (size_t)L_ * K3_, (size_t)L_ * K3_, (size_t)L_ * L_);
    k_patchsum<<<dim3(9 * L_, 1, G), dim3(256), 0, stream>>>(U, V, nv, sb);
    k_fsm<<<dim3(L_, G), dim3(256), 0, stream>>>(V, mm, Abuf, sb);
    gemm_bt<true><<<dim3(N9_ / 128, L_ / 128, G), dim3(256), 0, stream>>>(
        Abuf, XpT, (void*)Pbuf, N9_, L_,
        (size_t)L_ * L_, (size_t)N9_ * L_, (size_t)L_ * N9_);
    k_scatter<<<dim3((G * H_ * W_ * C_) / 256), dim3(256), 0, stream>>>(
        Pbuf, out + (size_t)sb * H_ * W_ * C_);
  }
}

// Round 4
// 258.486 us; speedup vs baseline: 1.7996x; 1.1184x over previous
//
#include <hip/hip_runtime.h>
#include <stdint.h>
#include <string.h>

// ContextualAttention on MI355X.
// Pipeline:
//  k_down:    x -> (bf16x3 packed F3a/F3b for Gram GEMM) + per-pixel sumsq S
//  k_mask:    mask -> 2x2 avg-pooled md
//  k_mmnorm:  md,S -> mm (valid-patch mask), ninv (1/patch-norm)
//  k_xpack:   x -> XpT[j=(a,b,c)][l=(p,q)] bf16 (deconv weights, transposed for GEMM B)
//  gemm_bt<false>: U = F3a . F3b^T   (Gram matrix, fp32-accurate via bf16x3)
//  k_patchsum:V[hw][pq] = 9-tap diag stencil of U * ninv[pq]  (shift = s*(L+1))
//  k_fsm:     fused fuse1 + fuse2 + masked softmax -> A (bf16), branch-free transpose map
//  gemm_bt<true>:  P(bf16) = A . XpT^T
//  k_scatter: out = parity-gather of P / 4

namespace {

constexpr int B_ = 4;
constexpr int H_ = 96;
constexpr int W_ = 96;
constexpr int C_ = 128;
constexpr int h_ = 48;
constexpr int L_ = 2304;   // h_*h_
constexpr int N9_ = 1152;  // 9*C_
constexpr int K3_ = 384;   // 3*C_  bf16x3 packed K
constexpr float SCALE_ = 10.0f;
constexpr float EPS_ = 1e-4f;

typedef unsigned short u16;
typedef __attribute__((ext_vector_type(8))) short bfrag8;   // 8 bf16 (4 VGPRs)
typedef __attribute__((ext_vector_type(4))) float f32x4;    // 4 fp32 acc

__device__ __forceinline__ u16 f2bf(float f) {
  uint32_t x;
  __builtin_memcpy(&x, &f, 4);
  uint32_t lsb = (x >> 16) & 1u;
  x += 0x7fffu + lsb;
  return (u16)(x >> 16);
}
__device__ __forceinline__ float bf2f(u16 u) {
  uint32_t v = ((uint32_t)u) << 16;
  float f;
  __builtin_memcpy(&f, &v, 4);
  return f;
}

// async global(16B/lane) -> LDS (wave-uniform base + lane*16)
__device__ __forceinline__ void gload16(const u16* g, u16* l) {
  __builtin_amdgcn_global_load_lds(
      (const __attribute__((address_space(1))) void*)g,
      (__attribute__((address_space(3))) void*)l, 16, 0, 0);
}

// XCD-chunked bijective block swizzle (m204 variant, any nwg)
__device__ __forceinline__ int xcd_swz8(int orig, int nwg) {
  int q = nwg >> 3, r = nwg & 7;
  int xcd = orig & 7, pos = orig >> 3;
  return (xcd < r ? xcd * (q + 1) : r * (q + 1) + (xcd - r) * q) + pos;
}

// ---- downscale (2x2 avg) + bf16x3 pack + per-pixel sum of squares -------
__global__ __launch_bounds__(128) void k_down(const float* __restrict__ x,
                                              u16* __restrict__ F3a,
                                              u16* __restrict__ F3b,
                                              float* __restrict__ S) {
  int blk = blockIdx.x;
  int b = blk / L_, l = blk % L_;
  int p = l / h_, q = l % h_;
  int c = threadIdx.x;
  const float* xb = x + (((size_t)b * H_ + 2 * p) * W_ + 2 * q) * C_ + c;
  float v = 0.25f * (xb[0] + xb[C_] + xb[(size_t)W_ * C_] + xb[(size_t)W_ * C_ + C_]);
  u16 hi = f2bf(v);
  u16 lo = f2bf(v - bf2f(hi));
  size_t base = ((size_t)b * L_ + l) * K3_;
  F3a[base + c] = hi; F3a[base + 128 + c] = hi; F3a[base + 256 + c] = lo;
  F3b[base + c] = hi; F3b[base + 128 + c] = lo; F3b[base + 256 + c] = hi;
  __shared__ float red[128];
  red[c] = v * v;
  __syncthreads();
  for (int s2 = 64; s2 > 0; s2 >>= 1) {
    if (c < s2) red[c] += red[c + s2];
    __syncthreads();
  }
  if (c == 0) S[(size_t)b * L_ + l] = red[0];
}

// ---- mask 2x2 avg-pool --------------------------------------------------
__global__ __launch_bounds__(256) void k_mask(const float* __restrict__ mask,
                                              float* __restrict__ md) {
  int i = blockIdx.x * 256 + threadIdx.x;
  int b = i / L_, l = i % L_, p = l / h_, q = l % h_;
  const float* mb = mask + ((size_t)b * H_ + 2 * p) * W_ + 2 * q;
  md[i] = 0.25f * (mb[0] + mb[1] + mb[W_] + mb[W_ + 1]);
}

// ---- valid-patch mask + 1/patch-norm ------------------------------------
__global__ __launch_bounds__(256) void k_mmnorm(const float* __restrict__ S,
                                                const float* __restrict__ md,
                                                float* __restrict__ mm,
                                                float* __restrict__ ninv) {
  int i = blockIdx.x * 256 + threadIdx.x;
  int b = i / L_, l = i % L_, p = l / h_, q = l % h_;
  float ssum = 0.f, msum = 0.f;
#pragma unroll
  for (int a = 0; a < 3; a++) {
    int rp = p - 1 + a;
#pragma unroll
    for (int bb = 0; bb < 3; bb++) {
      int rq = q - 1 + bb;
      bool ok = ((unsigned)rp < (unsigned)h_) && ((unsigned)rq < (unsigned)h_);
      int idx = ok ? (b * L_ + rp * h_ + rq) : 0;
      float sv = S[idx], mv = md[idx];
      if (ok) { ssum += sv; msum += mv; }
    }
  }
  mm[i] = (msum == 0.f) ? 1.f : 0.f;
  float n = fmaxf(sqrtf(ssum), EPS_);
  ninv[i] = 1.f / n;
}

// ---- pack deconv weights transposed: XpT[bz][j=(a,bb,c)][l=(p,q)] -------
__global__ __launch_bounds__(256) void k_xpack(const float* __restrict__ x,
                                               u16* __restrict__ XpT) {
  int lt = blockIdx.x * 32, jt = blockIdx.y * 64, bz = blockIdx.z;
  __shared__ u16 tile[32][65];
  int t = threadIdx.x;
  int jj = t & 63, lq = t >> 6;
  for (int pass = 0; pass < 8; ++pass) {
    int ll = pass * 4 + lq;
    int l = lt + ll;
    int p = l / h_, q = l % h_;
    int j = jt + jj;
    int a = j / 384, rem = j % 384, bb = rem / 128, c = rem % 128;
    int gy = 2 * p + a, gx = 2 * q + bb;
    float v = 0.f;
    if (gy < H_ && gx < W_) v = x[(((size_t)bz * H_ + gy) * W_ + gx) * C_ + c];
    tile[ll][jj] = f2bf(v);
  }
  __syncthreads();
  int lw = t & 31, jq = t >> 5;
  for (int pass = 0; pass < 8; ++pass) {
    int j2 = pass * 8 + jq;
    XpT[((size_t)bz * N9_ + jt + j2) * L_ + lt + lw] = tile[lw][j2];
  }
}

// ---- MFMA GEMM (m97 structure): C[m][n] = sum_k A[m][k]*B[n][k] ---------
template <bool OUTBF>
__global__ __launch_bounds__(256) void gemm_bt(const u16* __restrict__ A,
                                               const u16* __restrict__ B,
                                               void* __restrict__ Cv,
                                               int N, int Kd,
                                               size_t sA, size_t sB, size_t sC) {
  const u16* Ab = A + (size_t)blockIdx.z * sA;
  const u16* Bb = B + (size_t)blockIdx.z * sB;
  int nwg = gridDim.x * gridDim.y;
  int orig = blockIdx.y * gridDim.x + blockIdx.x;
  int wgid = xcd_swz8(orig, nwg);
  int bx = wgid % gridDim.x, by = wgid / gridDim.x;
  int m0 = by * 128, n0 = bx * 128;

  __shared__ u16 As[128 * 32];
  __shared__ u16 Bs[128 * 32];
  int t = threadIdx.x;
  int lane = t & 63, wv = t >> 6, wr = wv >> 1, wc = wv & 1;
  int mrow = lane & 15, kg = lane >> 4;
  f32x4 acc[4][4];
#pragma unroll
  for (int i = 0; i < 4; i++)
#pragma unroll
    for (int j = 0; j < 4; j++) acc[i][j] = (f32x4)(0.0f);

  int row = t >> 2, kc = t & 3;
  const u16* ga0 = Ab + (size_t)(m0 + row) * Kd + kc * 8;
  const u16* ga1 = ga0 + (size_t)64 * Kd;
  const u16* gb0 = Bb + (size_t)(n0 + row) * Kd + kc * 8;
  const u16* gb1 = gb0 + (size_t)64 * Kd;
  u16* lA0 = As + wv * 512;
  u16* lA1 = As + 2048 + wv * 512;
  u16* lB0 = Bs + wv * 512;
  u16* lB1 = Bs + 2048 + wv * 512;

  for (int k0 = 0; k0 < Kd; k0 += 32) {
    __syncthreads();
    gload16(ga0 + k0, lA0);
    gload16(ga1 + k0, lA1);
    gload16(gb0 + k0, lB0);
    gload16(gb1 + k0, lB1);
    __syncthreads();
    bfrag8 af[4], bf[4];
#pragma unroll
    for (int i = 0; i < 4; i++)
      af[i] = *(const bfrag8*)&As[(wr * 64 + i * 16 + mrow) * 32 + kg * 8];
#pragma unroll
    for (int i = 0; i < 4; i++)
      bf[i] = *(const bfrag8*)&Bs[(wc * 64 + i * 16 + mrow) * 32 + kg * 8];
#pragma unroll
    for (int i = 0; i < 4; i++)
#pragma unroll
      for (int j = 0; j < 4; j++)
        acc[i][j] = __builtin_amdgcn_mfma_f32_16x16x32_bf16(af[i], bf[j], acc[i][j], 0, 0, 0);
  }
#pragma unroll
  for (int i = 0; i < 4; i++)
#pragma unroll
    for (int j = 0; j < 4; j++)
#pragma unroll
      for (int r = 0; r < 4; r++) {
        int gr = m0 + wr * 64 + i * 16 + kg * 4 + r;
        int gc = n0 + wc * 64 + j * 16 + mrow;
        if (OUTBF) {
          ((u16*)Cv)[(size_t)blockIdx.z * sC + (size_t)gr * N + gc] = f2bf(acc[i][j][r]);
        } else {
          ((float*)Cv)[(size_t)blockIdx.z * sC + (size_t)gr * N + gc] = acc[i][j][r];
        }
      }
}

// ---- 9-tap diagonal patch-sum * 1/norm ----------------------------------
// off(a,b) = base + (48(a-1)+(b-1))*(L+1); validity separable + precomputed.
__global__ __launch_bounds__(256) void k_patchsum(const float* __restrict__ U,
                                                  float* __restrict__ V,
                                                  const float* __restrict__ ninv,
                                                  int b0) {
  int bx = xcd_swz8(blockIdx.x, 9 * L_), bz = blockIdx.z;
  int col = (bx % 9) * 256 + threadIdx.x;
  int R = bx / 9;
  const float* Ub = U + (size_t)bz * L_ * L_;
  float* Vb = V + (size_t)bz * L_ * L_;
  int hq = R / h_, wq = R % h_, ps = col / h_, qs = col % h_;
  bool ra[3], rb[3], ca[3], cb[3];
#pragma unroll
  for (int a = 0; a < 3; a++) {
    ra[a] = (unsigned)(hq - 1 + a) < (unsigned)h_;
    rb[a] = (unsigned)(wq - 1 + a) < (unsigned)h_;
    ca[a] = (unsigned)(ps - 1 + a) < (unsigned)h_;
    cb[a] = (unsigned)(qs - 1 + a) < (unsigned)h_;
  }
  int base = R * L_ + col;
  float s = 0.f;
#pragma unroll
  for (int a = 0; a < 3; a++) {
#pragma unroll
    for (int b = 0; b < 3; b++) {
      int sh = (a - 1) * h_ + (b - 1);
      bool ok = ra[a] && rb[b] && ca[a] && cb[b];
      uint32_t off = ok ? (uint32_t)(base + sh * (L_ + 1)) : 0u;
      float v = Ub[off];
      s += ok ? v : 0.f;
    }
  }
  Vb[(uint32_t)base] = s * ninv[(size_t)(b0 + bz) * L_ + col];
}

// ---- fused fuse1 + fuse2 + masked softmax -> bf16 attention -------------
// Transposed-flat shifts collapse to branch values:
//   T(T(j)-1) = j-48 (jy>0) else j+2255 ; T(T(j)+1) = j+48 (jy<47) else j-2255.
__global__ __launch_bounds__(256) void k_fsm(const float* __restrict__ V1,
                                             const float* __restrict__ mm,
                                             u16* __restrict__ Aout,
                                             int b0) {
  int i = xcd_swz8(blockIdx.x, L_), bz = blockIdx.y;
  int hq = i / h_, wq = i % h_;
  const float* Vb = V1 + (size_t)bz * L_ * L_;
  const float* mmb = mm + (size_t)(b0 + bz) * L_;
  u16* arow = Aout + ((size_t)bz * L_ + i) * L_;
  int t = threadIdx.x;

  // block-uniform row machinery
  uint32_t rowBase[3];
  bool rw0[3], rw1[3], rw2[3];  // rw*[d2] for d1 = -1, 0, +1
#pragma unroll
  for (int d2 = 0; d2 < 3; d2++) {
    int TA = wq * h_ + hq + (d2 - 1);
    bool ok = (TA >= 0) && (TA < L_);
    int TAc = ok ? TA : 0;
    int iB = (TAc % h_) * h_ + TAc / h_;
    rowBase[d2] = (uint32_t)(iB * L_);
    rw0[d2] = ok && (iB - 1 >= 0);
    rw1[d2] = ok;
    rw2[d2] = ok && (iB + 1 < L_);
  }

  int jy = t / h_, jx = t % h_;
  float y[9];
  float mx = -3.0e38f;
#pragma unroll
  for (int cc = 0; cc < 9; cc++) {
    int j = cc * 256 + t;
    int jB0 = (jy >= 1) ? (j - h_) : (j + (L_ - h_ - 1));
    int jB1 = j;
    int jB2 = (jy <= h_ - 2) ? (j + h_) : (j - (L_ - h_ - 1));
    bool tb0 = (j > 0), tb2 = (j < L_ - 1);
    float s = 0.f;
    // band d2=0
    {
      uint32_t oc = rowBase[0] + (uint32_t)jB0;
      bool w0 = rw0[0] && tb0 && (jB0 > 0);
      bool w1 = rw1[0] && tb0;
      bool w2 = rw2[0] && tb0 && (jB0 < L_ - 1);
      float vm = Vb[w0 ? oc - (L_ + 1) : 0u];
      float vc = Vb[w1 ? oc : 0u];
      float vp = Vb[w2 ? oc + (L_ + 1) : 0u];
      s += (w0 ? vm : 0.f) + (w1 ? vc : 0.f) + (w2 ? vp : 0.f);
    }
    // band d2=1 (center; TB always in range)
    {
      uint32_t oc = rowBase[1] + (uint32_t)jB1;
      bool w0 = rw0[1] && (jB1 > 0);
      bool w1 = rw1[1];
      bool w2 = rw2[1] && (jB1 < L_ - 1);
      float vm = Vb[w0 ? oc - (L_ + 1) : 0u];
      float vc = Vb[w1 ? oc : 0u];
      float vp = Vb[w2 ? oc + (L_ + 1) : 0u];
      s += (w0 ? vm : 0.f) + (w1 ? vc : 0.f) + (w2 ? vp : 0.f);
    }
    // band d2=2
    {
      uint32_t oc = rowBase[2] + (uint32_t)jB2;
      bool w0 = rw0[2] && tb2 && (jB2 > 0);
      bool w1 = rw1[2] && tb2;
      bool w2 = rw2[2] && tb2 && (jB2 < L_ - 1);
      float vm = Vb[w0 ? oc - (L_ + 1) : 0u];
      float vc = Vb[w1 ? oc : 0u];
      float vp = Vb[w2 ? oc + (L_ + 1) : 0u];
      s += (w0 ? vm : 0.f) + (w1 ? vc : 0.f) + (w2 ? vp : 0.f);
    }
    float zv = s * mmb[j] * SCALE_;
    y[cc] = zv;
    mx = fmaxf(mx, zv);
    jx += 256 - 5 * h_;   // +16
    jy += 5;
    if (jx >= h_) { jx -= h_; jy += 1; }
  }

  int lane = t & 63, wid = t >> 6;
  __shared__ float wredm[4];
  __shared__ float wreds[4];
#pragma unroll
  for (int o = 32; o >= 1; o >>= 1) mx = fmaxf(mx, __shfl_xor(mx, o, 64));
  if (lane == 0) wredm[wid] = mx;
  __syncthreads();
  float MX = fmaxf(fmaxf(wredm[0], wredm[1]), fmaxf(wredm[2], wredm[3]));
  float sm = 0.f;
#pragma unroll
  for (int cc = 0; cc < 9; cc++) {
    y[cc] = __expf(y[cc] - MX);
    sm += y[cc];
  }
#pragma unroll
  for (int o = 32; o >= 1; o >>= 1) sm += __shfl_xor(sm, o, 64);
  if (lane == 0) wreds[wid] = sm;
  __syncthreads();
  float inv = 1.0f / (wreds[0] + wreds[1] + wreds[2] + wreds[3]);
#pragma unroll
  for (int cc = 0; cc < 9; cc++) {
    int j = cc * 256 + t;
    arow[j] = f2bf(y[cc] * inv * mmb[j]);
  }
}

// ---- deconv parity-gather scatter (P is bf16) ---------------------------
__global__ __launch_bounds__(256) void k_scatter(const u16* __restrict__ P,
                                                 float* __restrict__ out) {
  int idx = blockIdx.x * 256 + threadIdx.x;
  int c = idx & 127;
  int r = idx >> 7;
  int xx = r % W_; r /= W_;
  int y = r % H_;
  int bz = r / H_;
  const u16* Pb = P + (size_t)bz * L_ * N9_;
  int yo[2], ya[2], ny = 0;
  if (y & 1) { yo[0] = y >> 1; ya[0] = 1; ny = 1; }
  else {
    yo[0] = y >> 1; ya[0] = 0; ny = 1;
    if (y >= 2) { yo[1] = (y >> 1) - 1; ya[1] = 2; ny = 2; }
  }
  int xo[2], xa[2], nx = 0;
  if (xx & 1) { xo[0] = xx >> 1; xa[0] = 1; nx = 1; }
  else {
    xo[0] = xx >> 1; xa[0] = 0; nx = 1;
    if (xx >= 2) { xo[1] = (xx >> 1) - 1; xa[1] = 2; nx = 2; }
  }
  float s = 0.f;
  for (int i = 0; i < ny; i++)
    for (int j = 0; j < nx; j++)
      s += bf2f(Pb[(size_t)(yo[i] * h_ + xo[j]) * N9_ + (ya[i] * 3 + xa[j]) * C_ + c]);
  out[((size_t)bz * H_ + y) * (size_t)W_ * C_ + (size_t)xx * C_ + c] = 0.25f * s;
}

}  // namespace

extern "C" void kernel_launch(void* const* d_in, const int* in_sizes, int n_in,
                              void* d_out, int out_size, void* d_ws, size_t ws_size,
                              hipStream_t stream) {
  (void)in_sizes; (void)n_in; (void)out_size;
  const float* x = (const float*)d_in[0];
  const float* mask = (const float*)d_in[1];
  float* out = (float*)d_out;
  char* ws = (char*)d_ws;

  const size_t szF3 = (size_t)B_ * L_ * K3_ * sizeof(u16);
  const size_t szSm = (size_t)B_ * L_ * sizeof(float);
  const size_t off_F3a = 0;
  const size_t off_F3b = off_F3a + szF3;
  const size_t off_S = off_F3b + szF3;
  const size_t off_md = off_S + szSm;
  const size_t off_mm = off_md + szSm;
  const size_t off_nv = off_mm + szSm;
  const size_t off_fixed_end = off_nv + szSm;

  const size_t perXp = (size_t)N9_ * L_ * sizeof(u16);
  const size_t perUV = (size_t)L_ * L_ * sizeof(float);
  int G = 4;
  while (G > 1 && off_fixed_end + (size_t)G * (perXp + 2 * perUV) > ws_size) G >>= 1;

  const size_t off_XpT = off_fixed_end;
  const size_t off_U = off_XpT + (size_t)G * perXp;
  const size_t off_V = off_U + (size_t)G * perUV;

  u16* F3a = (u16*)(ws + off_F3a);
  u16* F3b = (u16*)(ws + off_F3b);
  float* S = (float*)(ws + off_S);
  float* md = (float*)(ws + off_md);
  float* mm = (float*)(ws + off_mm);
  float* nv = (float*)(ws + off_nv);
  u16* XpT = (u16*)(ws + off_XpT);
  float* U = (float*)(ws + off_U);
  float* V = (float*)(ws + off_V);
  u16* Abuf = (u16*)(ws + off_U);                                      // alias U lower half
  u16* Pbuf = (u16*)(ws + off_U + (size_t)G * L_ * L_ * sizeof(u16));  // alias after A

  k_down<<<dim3(B_ * L_), dim3(C_), 0, stream>>>(x, F3a, F3b, S);
  k_mask<<<dim3((B_ * L_) / 256), dim3(256), 0, stream>>>(mask, md);
  k_mmnorm<<<dim3((B_ * L_) / 256), dim3(256), 0, stream>>>(S, md, mm, nv);

  for (int sb = 0; sb < B_; sb += G) {
    const float* xs = x + (size_t)sb * H_ * W_ * C_;
    k_xpack<<<dim3(L_ / 32, N9_ / 64, G), dim3(256), 0, stream>>>(xs, XpT);
    gemm_bt<false><<<dim3(L_ / 128, L_ / 128, G), dim3(256), 0, stream>>>(
        F3a + (size_t)sb * L_ * K3_, F3b + (size_t)sb * L_ * K3_, (void*)U,
        L_, K3_, (size_t)L_ * K3_, (size_t)L_ * K3_, (size_t)L_ * L_);
    k_patchsum<<<dim3(9 * L_, 1, G), dim3(256), 0, stream>>>(U, V, nv, sb);
    k_fsm<<<dim3(L_, G), dim3(256), 0, stream>>>(V, mm, Abuf, sb);
    gemm_bt<true><<<dim3(N9_ / 128, L_ / 128, G), dim3(256), 0, stream>>>(
        Abuf, XpT, (void*)Pbuf, N9_, L_,
        (size_t)L_ * L_, (size_t)N9_ * L_, (size_t)L_ * N9_);
    k_scatter<<<dim3((G * H_ * W_ * C_) / 256), dim3(256), 0, stream>>>(
        Pbuf, out + (size_t)sb * H_ * W_ * C_);
  }
}

// Round 5
// 242.593 us; speedup vs baseline: 1.9175x; 1.0655x over previous
//
#include <hip/hip_runtime.h>
#include <hip/hip_fp16.h>
#include <stdint.h>
#include <string.h>

// ContextualAttention on MI355X.
// Pipeline:
//  k_down:    x -> (bf16x3 packed F3a/F3b for Gram GEMM) + per-pixel sumsq S
//  k_mask:    mask -> 2x2 avg-pooled md
//  k_mmnorm:  md,S -> mm (valid-patch mask), ninv (1/patch-norm)
//  k_xpack:   x -> XpT[j=(a,b,c)][l=(p,q)] bf16 (deconv weights, transposed for GEMM B)
//  gemm_bt<F16>: U(fp16) = F3a . F3b^T   (Gram, fp32-accurate via bf16x3)
//  k_patchsum:V(fp32)[hw][pq] = 9-tap diag stencil of U * ninv[pq]
//  k_fsm:     fused fuse1 + fuse2 + masked softmax -> A (bf16)
//  gemm_bt<BF16>: P(bf16) = A . XpT^T
//  k_scatter: out = parity-gather of P / 4
// GEMM: min-2-phase double-buffered LDS + global_load_lds(16B) with
// both-sides XOR swizzle (byte ^= ((byte>>7)&7)<<4) killing the 8-way
// ds_read_b128 conflict.

namespace {

constexpr int B_ = 4;
constexpr int H_ = 96;
constexpr int W_ = 96;
constexpr int C_ = 128;
constexpr int h_ = 48;
constexpr int L_ = 2304;   // h_*h_
constexpr int N9_ = 1152;  // 9*C_
constexpr int K3_ = 384;   // 3*C_  bf16x3 packed K
constexpr float SCALE_ = 10.0f;
constexpr float EPS_ = 1e-4f;

constexpr int OUT_F16 = 1;
constexpr int OUT_BF16 = 2;

typedef unsigned short u16;
typedef __attribute__((ext_vector_type(8))) short bfrag8;   // 8 bf16 (4 VGPRs)
typedef __attribute__((ext_vector_type(4))) float f32x4;    // 4 fp32 acc

__device__ __forceinline__ u16 f2bf(float f) {
  uint32_t x;
  __builtin_memcpy(&x, &f, 4);
  uint32_t lsb = (x >> 16) & 1u;
  x += 0x7fffu + lsb;
  return (u16)(x >> 16);
}
__device__ __forceinline__ float bf2f(u16 u) {
  uint32_t v = ((uint32_t)u) << 16;
  float f;
  __builtin_memcpy(&f, &v, 4);
  return f;
}
__device__ __forceinline__ u16 f2h(float f) {
  __half h = __float2half(f);
  u16 u;
  __builtin_memcpy(&u, &h, 2);
  return u;
}
__device__ __forceinline__ float h2f(u16 u) {
  __half h;
  __builtin_memcpy(&h, &u, 2);
  return __half2float(h);
}

// async global(16B/lane) -> LDS (wave-uniform base + lane*16)
__device__ __forceinline__ void gload16(const u16* g, void* l) {
  __builtin_amdgcn_global_load_lds(
      (const __attribute__((address_space(1))) void*)g,
      (__attribute__((address_space(3))) void*)l, 16, 0, 0);
}

// XCD-chunked bijective block swizzle (m204 variant, any nwg)
__device__ __forceinline__ int xcd_swz8(int orig, int nwg) {
  int q = nwg >> 3, r = nwg & 7;
  int xcd = orig & 7, pos = orig >> 3;
  return (xcd < r ? xcd * (q + 1) : r * (q + 1) + (xcd - r) * q) + pos;
}

// LDS byte-offset swizzle (involution): XOR row bits[3:1] onto 16B-slot bits.
__device__ __forceinline__ uint32_t swzb(uint32_t byte) {
  return byte ^ (((byte >> 7) & 7u) << 4);
}

// ---- downscale (2x2 avg) + bf16x3 pack + per-pixel sum of squares -------
__global__ __launch_bounds__(128) void k_down(const float* __restrict__ x,
                                              u16* __restrict__ F3a,
                                              u16* __restrict__ F3b,
                                              float* __restrict__ S) {
  int blk = blockIdx.x;
  int b = blk / L_, l = blk % L_;
  int p = l / h_, q = l % h_;
  int c = threadIdx.x;
  const float* xb = x + (((size_t)b * H_ + 2 * p) * W_ + 2 * q) * C_ + c;
  float v = 0.25f * (xb[0] + xb[C_] + xb[(size_t)W_ * C_] + xb[(size_t)W_ * C_ + C_]);
  u16 hi = f2bf(v);
  u16 lo = f2bf(v - bf2f(hi));
  size_t base = ((size_t)b * L_ + l) * K3_;
  F3a[base + c] = hi; F3a[base + 128 + c] = hi; F3a[base + 256 + c] = lo;
  F3b[base + c] = hi; F3b[base + 128 + c] = lo; F3b[base + 256 + c] = hi;
  __shared__ float red[128];
  red[c] = v * v;
  __syncthreads();
  for (int s2 = 64; s2 > 0; s2 >>= 1) {
    if (c < s2) red[c] += red[c + s2];
    __syncthreads();
  }
  if (c == 0) S[(size_t)b * L_ + l] = red[0];
}

// ---- mask 2x2 avg-pool --------------------------------------------------
__global__ __launch_bounds__(256) void k_mask(const float* __restrict__ mask,
                                              float* __restrict__ md) {
  int i = blockIdx.x * 256 + threadIdx.x;
  int b = i / L_, l = i % L_, p = l / h_, q = l % h_;
  const float* mb = mask + ((size_t)b * H_ + 2 * p) * W_ + 2 * q;
  md[i] = 0.25f * (mb[0] + mb[1] + mb[W_] + mb[W_ + 1]);
}

// ---- valid-patch mask + 1/patch-norm ------------------------------------
__global__ __launch_bounds__(256) void k_mmnorm(const float* __restrict__ S,
                                                const float* __restrict__ md,
                                                float* __restrict__ mm,
                                                float* __restrict__ ninv) {
  int i = blockIdx.x * 256 + threadIdx.x;
  int b = i / L_, l = i % L_, p = l / h_, q = l % h_;
  float ssum = 0.f, msum = 0.f;
#pragma unroll
  for (int a = 0; a < 3; a++) {
    int rp = p - 1 + a;
#pragma unroll
    for (int bb = 0; bb < 3; bb++) {
      int rq = q - 1 + bb;
      bool ok = ((unsigned)rp < (unsigned)h_) && ((unsigned)rq < (unsigned)h_);
      int idx = ok ? (b * L_ + rp * h_ + rq) : 0;
      float sv = S[idx], mv = md[idx];
      if (ok) { ssum += sv; msum += mv; }
    }
  }
  mm[i] = (msum == 0.f) ? 1.f : 0.f;
  float n = fmaxf(sqrtf(ssum), EPS_);
  ninv[i] = 1.f / n;
}

// ---- pack deconv weights transposed: XpT[bz][j=(a,bb,c)][l=(p,q)] -------
__global__ __launch_bounds__(256) void k_xpack(const float* __restrict__ x,
                                               u16* __restrict__ XpT) {
  int lt = blockIdx.x * 32, jt = blockIdx.y * 64, bz = blockIdx.z;
  __shared__ u16 tile[32][65];
  int t = threadIdx.x;
  int jj = t & 63, lq = t >> 6;
  for (int pass = 0; pass < 8; ++pass) {
    int ll = pass * 4 + lq;
    int l = lt + ll;
    int p = l / h_, q = l % h_;
    int j = jt + jj;
    int a = j / 384, rem = j % 384, bb = rem / 128, c = rem % 128;
    int gy = 2 * p + a, gx = 2 * q + bb;
    float v = 0.f;
    if (gy < H_ && gx < W_) v = x[(((size_t)bz * H_ + gy) * W_ + gx) * C_ + c];
    tile[ll][jj] = f2bf(v);
  }
  __syncthreads();
  int lw = t & 31, jq = t >> 5;
  for (int pass = 0; pass < 8; ++pass) {
    int j2 = pass * 8 + jq;
    XpT[((size_t)bz * N9_ + jt + j2) * L_ + lt + lw] = tile[lw][j2];
  }
}

// ---- MFMA GEMM: C[m][n] = sum_k A[m][k]*B[n][k] -------------------------
// 128x128 tile, 4 waves (2x2), BK=32, min-2-phase double buffer,
// global_load_lds(16B) with pre-swizzled source + swizzled ds_read.
template <int OUT>
__global__ __launch_bounds__(256) void gemm_bt(const u16* __restrict__ A,
                                               const u16* __restrict__ B,
                                               void* __restrict__ Cv,
                                               int N, int Kd,
                                               size_t sA, size_t sB, size_t sC) {
  const u16* Ab = A + (size_t)blockIdx.z * sA;
  const u16* Bb = B + (size_t)blockIdx.z * sB;
  int nwg = gridDim.x * gridDim.y;
  int orig = blockIdx.y * gridDim.x + blockIdx.x;
  int wgid = xcd_swz8(orig, nwg);
  int bx = wgid % gridDim.x, by = wgid / gridDim.x;
  int m0 = by * 128, n0 = bx * 128;

  __shared__ char As[2][8192];
  __shared__ char Bs[2][8192];
  int t = threadIdx.x;
  int lane = t & 63, wv = t >> 6, wr = wv >> 1, wc = wv & 1;
  int mrow = lane & 15, kg = lane >> 4;
  f32x4 acc[4][4];
#pragma unroll
  for (int i = 0; i < 4; i++)
#pragma unroll
    for (int j = 0; j < 4; j++) acc[i][j] = (f32x4)(0.0f);

  // staging: dest is linear (byte t*16 within half-tile); source chunk is the
  // swizzle-image so that swizzled reads find their logical data.
  uint32_t d16 = (uint32_t)t * 16u;
  uint32_t sz = swzb(d16);
  int rowp = (int)(sz >> 6);        // 0..63 permuted row
  int kcp = (int)((sz >> 4) & 3u);  // permuted 16B chunk in row
  const u16* ga0 = Ab + (size_t)(m0 + rowp) * Kd + kcp * 8;
  const u16* ga1 = Ab + (size_t)(m0 + 64 + rowp) * Kd + kcp * 8;
  const u16* gb0 = Bb + (size_t)(n0 + rowp) * Kd + kcp * 8;
  const u16* gb1 = Bb + (size_t)(n0 + 64 + rowp) * Kd + kcp * 8;

  auto STAGE = [&](int buf, int k0) {
    gload16(ga0 + k0, As[buf] + wv * 1024);
    gload16(ga1 + k0, As[buf] + 4096 + wv * 1024);
    gload16(gb0 + k0, Bs[buf] + wv * 1024);
    gload16(gb1 + k0, Bs[buf] + 4096 + wv * 1024);
  };

  int nsteps = Kd >> 5;
  STAGE(0, 0);
  __syncthreads();   // buf0 staged (compiler drains vmcnt before barrier)
  int cur = 0;
  for (int s = 0; s < nsteps; ++s) {
    if (s + 1 < nsteps) STAGE(cur ^ 1, (s + 1) << 5);  // prefetch next tile
    bfrag8 af[4], bf[4];
#pragma unroll
    for (int i = 0; i < 4; i++) {
      uint32_t byte = (uint32_t)(wr * 64 + i * 16 + mrow) * 64u + (uint32_t)kg * 16u;
      af[i] = *(const bfrag8*)(As[cur] + swzb(byte));
    }
#pragma unroll
    for (int i = 0; i < 4; i++) {
      uint32_t byte = (uint32_t)(wc * 64 + i * 16 + mrow) * 64u + (uint32_t)kg * 16u;
      bf[i] = *(const bfrag8*)(Bs[cur] + swzb(byte));
    }
#pragma unroll
    for (int i = 0; i < 4; i++)
#pragma unroll
      for (int j = 0; j < 4; j++)
        acc[i][j] = __builtin_amdgcn_mfma_f32_16x16x32_bf16(af[i], bf[j], acc[i][j], 0, 0, 0);
    __syncthreads();   // drains prefetch (issued before compute) + read-protect
    cur ^= 1;
  }
  // C/D layout: col = lane&15, row = (lane>>4)*4 + reg
#pragma unroll
  for (int i = 0; i < 4; i++)
#pragma unroll
    for (int j = 0; j < 4; j++)
#pragma unroll
      for (int r = 0; r < 4; r++) {
        int gr = m0 + wr * 64 + i * 16 + kg * 4 + r;
        int gc = n0 + wc * 64 + j * 16 + mrow;
        if (OUT == OUT_BF16) {
          ((u16*)Cv)[(size_t)blockIdx.z * sC + (size_t)gr * N + gc] = f2bf(acc[i][j][r]);
        } else {
          ((u16*)Cv)[(size_t)blockIdx.z * sC + (size_t)gr * N + gc] = f2h(acc[i][j][r]);
        }
      }
}

// ---- 9-tap diagonal patch-sum * 1/norm (U fp16 in, V fp32 out) ----------
__global__ __launch_bounds__(256) void k_patchsum(const u16* __restrict__ U,
                                                  float* __restrict__ V,
                                                  const float* __restrict__ ninv,
                                                  int b0) {
  int bx = xcd_swz8(blockIdx.x, 9 * L_), bz = blockIdx.z;
  int col = (bx % 9) * 256 + threadIdx.x;
  int R = bx / 9;
  const u16* Ub = U + (size_t)bz * L_ * L_;
  float* Vb = V + (size_t)bz * L_ * L_;
  int hq = R / h_, wq = R % h_, ps = col / h_, qs = col % h_;
  bool ra[3], rb[3], ca[3], cb[3];
#pragma unroll
  for (int a = 0; a < 3; a++) {
    ra[a] = (unsigned)(hq - 1 + a) < (unsigned)h_;
    rb[a] = (unsigned)(wq - 1 + a) < (unsigned)h_;
    ca[a] = (unsigned)(ps - 1 + a) < (unsigned)h_;
    cb[a] = (unsigned)(qs - 1 + a) < (unsigned)h_;
  }
  int base = R * L_ + col;
  float s = 0.f;
#pragma unroll
  for (int a = 0; a < 3; a++) {
#pragma unroll
    for (int b = 0; b < 3; b++) {
      int sh = (a - 1) * h_ + (b - 1);
      bool ok = ra[a] && rb[b] && ca[a] && cb[b];
      uint32_t off = ok ? (uint32_t)(base + sh * (L_ + 1)) : 0u;
      float v = h2f(Ub[off]);
      s += ok ? v : 0.f;
    }
  }
  Vb[(uint32_t)base] = s * ninv[(size_t)(b0 + bz) * L_ + col];
}

// ---- fused fuse1 + fuse2 + masked softmax -> bf16 attention -------------
// Transposed-flat shifts collapse to branch values:
//   T(T(j)-1) = j-48 (jy>0) else j+2255 ; T(T(j)+1) = j+48 (jy<47) else j-2255.
__global__ __launch_bounds__(256) void k_fsm(const float* __restrict__ V1,
                                             const float* __restrict__ mm,
                                             u16* __restrict__ Aout,
                                             int b0) {
  int i = xcd_swz8(blockIdx.x, L_), bz = blockIdx.y;
  int hq = i / h_, wq = i % h_;
  const float* Vb = V1 + (size_t)bz * L_ * L_;
  const float* mmb = mm + (size_t)(b0 + bz) * L_;
  u16* arow = Aout + ((size_t)bz * L_ + i) * L_;
  int t = threadIdx.x;

  uint32_t rowBase[3];
  bool rw0[3], rw1[3], rw2[3];
#pragma unroll
  for (int d2 = 0; d2 < 3; d2++) {
    int TA = wq * h_ + hq + (d2 - 1);
    bool ok = (TA >= 0) && (TA < L_);
    int TAc = ok ? TA : 0;
    int iB = (TAc % h_) * h_ + TAc / h_;
    rowBase[d2] = (uint32_t)(iB * L_);
    rw0[d2] = ok && (iB - 1 >= 0);
    rw1[d2] = ok;
    rw2[d2] = ok && (iB + 1 < L_);
  }

  int jy = t / h_, jx = t % h_;
  float y[9];
  float mx = -3.0e38f;
#pragma unroll
  for (int cc = 0; cc < 9; cc++) {
    int j = cc * 256 + t;
    int jB0 = (jy >= 1) ? (j - h_) : (j + (L_ - h_ - 1));
    int jB1 = j;
    int jB2 = (jy <= h_ - 2) ? (j + h_) : (j - (L_ - h_ - 1));
    bool tb0 = (j > 0), tb2 = (j < L_ - 1);
    float s = 0.f;
    {
      uint32_t oc = rowBase[0] + (uint32_t)jB0;
      bool w0 = rw0[0] && tb0 && (jB0 > 0);
      bool w1 = rw1[0] && tb0;
      bool w2 = rw2[0] && tb0 && (jB0 < L_ - 1);
      float vm = Vb[w0 ? oc - (L_ + 1) : 0u];
      float vc = Vb[w1 ? oc : 0u];
      float vp = Vb[w2 ? oc + (L_ + 1) : 0u];
      s += (w0 ? vm : 0.f) + (w1 ? vc : 0.f) + (w2 ? vp : 0.f);
    }
    {
      uint32_t oc = rowBase[1] + (uint32_t)jB1;
      bool w0 = rw0[1] && (jB1 > 0);
      bool w1 = rw1[1];
      bool w2 = rw2[1] && (jB1 < L_ - 1);
      float vm = Vb[w0 ? oc - (L_ + 1) : 0u];
      float vc = Vb[w1 ? oc : 0u];
      float vp = Vb[w2 ? oc + (L_ + 1) : 0u];
      s += (w0 ? vm : 0.f) + (w1 ? vc : 0.f) + (w2 ? vp : 0.f);
    }
    {
      uint32_t oc = rowBase[2] + (uint32_t)jB2;
      bool w0 = rw0[2] && tb2 && (jB2 > 0);
      bool w1 = rw1[2] && tb2;
      bool w2 = rw2[2] && tb2 && (jB2 < L_ - 1);
      float vm = Vb[w0 ? oc - (L_ + 1) : 0u];
      float vc = Vb[w1 ? oc : 0u];
      float vp = Vb[w2 ? oc + (L_ + 1) : 0u];
      s += (w0 ? vm : 0.f) + (w1 ? vc : 0.f) + (w2 ? vp : 0.f);
    }
    float zv = s * mmb[j] * SCALE_;
    y[cc] = zv;
    mx = fmaxf(mx, zv);
    jx += 256 - 5 * h_;   // +16
    jy += 5;
    if (jx >= h_) { jx -= h_; jy += 1; }
  }

  int lane = t & 63, wid = t >> 6;
  __shared__ float wredm[4];
  __shared__ float wreds[4];
#pragma unroll
  for (int o = 32; o >= 1; o >>= 1) mx = fmaxf(mx, __shfl_xor(mx, o, 64));
  if (lane == 0) wredm[wid] = mx;
  __syncthreads();
  float MX = fmaxf(fmaxf(wredm[0], wredm[1]), fmaxf(wredm[2], wredm[3]));
  float sm = 0.f;
#pragma unroll
  for (int cc = 0; cc < 9; cc++) {
    y[cc] = __expf(y[cc] - MX);
    sm += y[cc];
  }
#pragma unroll
  for (int o = 32; o >= 1; o >>= 1) sm += __shfl_xor(sm, o, 64);
  if (lane == 0) wreds[wid] = sm;
  __syncthreads();
  float inv = 1.0f / (wreds[0] + wreds[1] + wreds[2] + wreds[3]);
#pragma unroll
  for (int cc = 0; cc < 9; cc++) {
    int j = cc * 256 + t;
    arow[j] = f2bf(y[cc] * inv * mmb[j]);
  }
}

// ---- deconv parity-gather scatter (P is bf16) ---------------------------
__global__ __launch_bounds__(256) void k_scatter(const u16* __restrict__ P,
                                                 float* __restrict__ out) {
  int idx = blockIdx.x * 256 + threadIdx.x;
  int c = idx & 127;
  int r = idx >> 7;
  int xx = r % W_; r /= W_;
  int y = r % H_;
  int bz = r / H_;
  const u16* Pb = P + (size_t)bz * L_ * N9_;
  int yo[2], ya[2], ny = 0;
  if (y & 1) { yo[0] = y >> 1; ya[0] = 1; ny = 1; }
  else {
    yo[0] = y >> 1; ya[0] = 0; ny = 1;
    if (y >= 2) { yo[1] = (y >> 1) - 1; ya[1] = 2; ny = 2; }
  }
  int xo[2], xa[2], nx = 0;
  if (xx & 1) { xo[0] = xx >> 1; xa[0] = 1; nx = 1; }
  else {
    xo[0] = xx >> 1; xa[0] = 0; nx = 1;
    if (xx >= 2) { xo[1] = (xx >> 1) - 1; xa[1] = 2; nx = 2; }
  }
  float s = 0.f;
  for (int i = 0; i < ny; i++)
    for (int j = 0; j < nx; j++)
      s += bf2f(Pb[(size_t)(yo[i] * h_ + xo[j]) * N9_ + (ya[i] * 3 + xa[j]) * C_ + c]);
  out[((size_t)bz * H_ + y) * (size_t)W_ * C_ + (size_t)xx * C_ + c] = 0.25f * s;
}

}  // namespace

extern "C" void kernel_launch(void* const* d_in, const int* in_sizes, int n_in,
                              void* d_out, int out_size, void* d_ws, size_t ws_size,
                              hipStream_t stream) {
  (void)in_sizes; (void)n_in; (void)out_size;
  const float* x = (const float*)d_in[0];
  const float* mask = (const float*)d_in[1];
  float* out = (float*)d_out;
  char* ws = (char*)d_ws;

  const size_t szF3 = (size_t)B_ * L_ * K3_ * sizeof(u16);
  const size_t szSm = (size_t)B_ * L_ * sizeof(float);
  const size_t off_F3a = 0;
  const size_t off_F3b = off_F3a + szF3;
  const size_t off_S = off_F3b + szF3;
  const size_t off_md = off_S + szSm;
  const size_t off_mm = off_md + szSm;
  const size_t off_nv = off_mm + szSm;
  const size_t off_fixed_end = off_nv + szSm;

  const size_t perXp = (size_t)N9_ * L_ * sizeof(u16);   // 5.3 MB
  const size_t perU = (size_t)L_ * L_ * sizeof(u16);     // 10.6 MB (fp16)
  const size_t perV = (size_t)L_ * L_ * sizeof(float);   // 21.2 MB (fp32)
  int G = 4;
  while (G > 1 && off_fixed_end + (size_t)G * (perXp + perU + perV) > ws_size) G >>= 1;

  const size_t off_XpT = off_fixed_end;
  const size_t off_U = off_XpT + (size_t)G * perXp;
  const size_t off_V = off_U + (size_t)G * perU;

  u16* F3a = (u16*)(ws + off_F3a);
  u16* F3b = (u16*)(ws + off_F3b);
  float* S = (float*)(ws + off_S);
  float* md = (float*)(ws + off_md);
  float* mm = (float*)(ws + off_mm);
  float* nv = (float*)(ws + off_nv);
  u16* XpT = (u16*)(ws + off_XpT);
  u16* U = (u16*)(ws + off_U);
  float* V = (float*)(ws + off_V);
  u16* Abuf = (u16*)(ws + off_U);   // alias U (U dead after patchsum)
  u16* Pbuf = (u16*)(ws + off_V);   // alias V (V dead after fsm)

  k_down<<<dim3(B_ * L_), dim3(C_), 0, stream>>>(x, F3a, F3b, S);
  k_mask<<<dim3((B_ * L_) / 256), dim3(256), 0, stream>>>(mask, md);
  k_mmnorm<<<dim3((B_ * L_) / 256), dim3(256), 0, stream>>>(S, md, mm, nv);

  for (int sb = 0; sb < B_; sb += G) {
    const float* xs = x + (size_t)sb * H_ * W_ * C_;
    k_xpack<<<dim3(L_ / 32, N9_ / 64, G), dim3(256), 0, stream>>>(xs, XpT);
    gemm_bt<OUT_F16><<<dim3(L_ / 128, L_ / 128, G), dim3(256), 0, stream>>>(
        F3a + (size_t)sb * L_ * K3_, F3b + (size_t)sb * L_ * K3_, (void*)U,
        L_, K3_, (size_t)L_ * K3_, (size_t)L_ * K3_, (size_t)L_ * L_);
    k_patchsum<<<dim3(9 * L_, 1, G), dim3(256), 0, stream>>>(U, V, nv, sb);
    k_fsm<<<dim3(L_, G), dim3(256), 0, stream>>>(V, mm, Abuf, sb);
    gemm_bt<OUT_BF16><<<dim3(N9_ / 128, L_ / 128, G), dim3(256), 0, stream>>>(
        Abuf, XpT, (void*)Pbuf, N9_, L_,
        (size_t)L_ * L_, (size_t)N9_ * L_, (size_t)L_ * N9_);
    k_scatter<<<dim3((G * H_ * W_ * C_) / 256), dim3(256), 0, stream>>>(
        Pbuf, out + (size_t)sb * H_ * W_ * C_);
  }
}

// Round 6
// 225.318 us; speedup vs baseline: 2.0645x; 1.0767x over previous
//
#include <hip/hip_runtime.h>
#include <hip/hip_fp16.h>
#include <stdint.h>
#include <string.h>

// ContextualAttention on MI355X.
// Pipeline:
//  k_down:    x -> (bf16x3 packed F3a/F3b for Gram GEMM) + per-pixel sumsq S
//  k_mask:    mask -> 2x2 avg-pooled md
//  k_mmnorm:  md,S -> mm (valid-patch mask), ninv (1/patch-norm)
//  k_xpack:   x -> XpT[j=(a,b,c)][l=(p,q)] bf16 (deconv weights, transposed for GEMM B)
//  gemm_bt<F16>: U(fp16) = F3a . F3b^T   (Gram, fp32-accurate via bf16x3)
//  k_patchsum:V(fp32)[hw][pq] = 9-tap diag stencil of U * ninv[pq]  (8 outputs/thread,
//             unconditional imm-offset loads, value-masked)
//  k_fsm:     fused fuse1 + fuse2 + masked softmax -> A (bf16)
//  gemm_bt<BF16>: P(bf16) = A . XpT^T
//  k_scatter: out = parity-gather of P / 4

namespace {

constexpr int B_ = 4;
constexpr int H_ = 96;
constexpr int W_ = 96;
constexpr int C_ = 128;
constexpr int h_ = 48;
constexpr int L_ = 2304;   // h_*h_
constexpr int N9_ = 1152;  // 9*C_
constexpr int K3_ = 384;   // 3*C_  bf16x3 packed K
constexpr float SCALE_ = 10.0f;
constexpr float EPS_ = 1e-4f;

constexpr int OUT_F16 = 1;
constexpr int OUT_BF16 = 2;

typedef unsigned short u16;
typedef __attribute__((ext_vector_type(8))) short bfrag8;   // 8 bf16 (4 VGPRs)
typedef __attribute__((ext_vector_type(4))) float f32x4;    // 4 fp32 acc

__device__ __forceinline__ u16 f2bf(float f) {
  uint32_t x;
  __builtin_memcpy(&x, &f, 4);
  uint32_t lsb = (x >> 16) & 1u;
  x += 0x7fffu + lsb;
  return (u16)(x >> 16);
}
__device__ __forceinline__ float bf2f(u16 u) {
  uint32_t v = ((uint32_t)u) << 16;
  float f;
  __builtin_memcpy(&f, &v, 4);
  return f;
}
__device__ __forceinline__ u16 f2h(float f) {
  __half h = __float2half(f);
  u16 u;
  __builtin_memcpy(&u, &h, 2);
  return u;
}
__device__ __forceinline__ float h2f(u16 u) {
  __half h;
  __builtin_memcpy(&h, &u, 2);
  return __half2float(h);
}

// async global(16B/lane) -> LDS (wave-uniform base + lane*16)
__device__ __forceinline__ void gload16(const u16* g, void* l) {
  __builtin_amdgcn_global_load_lds(
      (const __attribute__((address_space(1))) void*)g,
      (__attribute__((address_space(3))) void*)l, 16, 0, 0);
}

// XCD-chunked bijective block swizzle (m204 variant, any nwg)
__device__ __forceinline__ int xcd_swz8(int orig, int nwg) {
  int q = nwg >> 3, r = nwg & 7;
  int xcd = orig & 7, pos = orig >> 3;
  return (xcd < r ? xcd * (q + 1) : r * (q + 1) + (xcd - r) * q) + pos;
}

// LDS byte-offset swizzle (involution): XOR row bits[3:1] onto 16B-slot bits.
__device__ __forceinline__ uint32_t swzb(uint32_t byte) {
  return byte ^ (((byte >> 7) & 7u) << 4);
}

// ---- downscale (2x2 avg) + bf16x3 pack + per-pixel sum of squares -------
__global__ __launch_bounds__(128) void k_down(const float* __restrict__ x,
                                              u16* __restrict__ F3a,
                                              u16* __restrict__ F3b,
                                              float* __restrict__ S) {
  int blk = blockIdx.x;
  int b = blk / L_, l = blk % L_;
  int p = l / h_, q = l % h_;
  int c = threadIdx.x;
  const float* xb = x + (((size_t)b * H_ + 2 * p) * W_ + 2 * q) * C_ + c;
  float v = 0.25f * (xb[0] + xb[C_] + xb[(size_t)W_ * C_] + xb[(size_t)W_ * C_ + C_]);
  u16 hi = f2bf(v);
  u16 lo = f2bf(v - bf2f(hi));
  size_t base = ((size_t)b * L_ + l) * K3_;
  F3a[base + c] = hi; F3a[base + 128 + c] = hi; F3a[base + 256 + c] = lo;
  F3b[base + c] = hi; F3b[base + 128 + c] = lo; F3b[base + 256 + c] = hi;
  __shared__ float red[128];
  red[c] = v * v;
  __syncthreads();
  for (int s2 = 64; s2 > 0; s2 >>= 1) {
    if (c < s2) red[c] += red[c + s2];
    __syncthreads();
  }
  if (c == 0) S[(size_t)b * L_ + l] = red[0];
}

// ---- mask 2x2 avg-pool --------------------------------------------------
__global__ __launch_bounds__(256) void k_mask(const float* __restrict__ mask,
                                              float* __restrict__ md) {
  int i = blockIdx.x * 256 + threadIdx.x;
  int b = i / L_, l = i % L_, p = l / h_, q = l % h_;
  const float* mb = mask + ((size_t)b * H_ + 2 * p) * W_ + 2 * q;
  md[i] = 0.25f * (mb[0] + mb[1] + mb[W_] + mb[W_ + 1]);
}

// ---- valid-patch mask + 1/patch-norm ------------------------------------
__global__ __launch_bounds__(256) void k_mmnorm(const float* __restrict__ S,
                                                const float* __restrict__ md,
                                                float* __restrict__ mm,
                                                float* __restrict__ ninv) {
  int i = blockIdx.x * 256 + threadIdx.x;
  int b = i / L_, l = i % L_, p = l / h_, q = l % h_;
  float ssum = 0.f, msum = 0.f;
#pragma unroll
  for (int a = 0; a < 3; a++) {
    int rp = p - 1 + a;
#pragma unroll
    for (int bb = 0; bb < 3; bb++) {
      int rq = q - 1 + bb;
      bool ok = ((unsigned)rp < (unsigned)h_) && ((unsigned)rq < (unsigned)h_);
      int idx = ok ? (b * L_ + rp * h_ + rq) : 0;
      float sv = S[idx], mv = md[idx];
      if (ok) { ssum += sv; msum += mv; }
    }
  }
  mm[i] = (msum == 0.f) ? 1.f : 0.f;
  float n = fmaxf(sqrtf(ssum), EPS_);
  ninv[i] = 1.f / n;
}

// ---- pack deconv weights transposed: XpT[bz][j=(a,bb,c)][l=(p,q)] -------
__global__ __launch_bounds__(256) void k_xpack(const float* __restrict__ x,
                                               u16* __restrict__ XpT) {
  int lt = blockIdx.x * 32, jt = blockIdx.y * 64, bz = blockIdx.z;
  __shared__ u16 tile[32][65];
  int t = threadIdx.x;
  int jj = t & 63, lq = t >> 6;
  for (int pass = 0; pass < 8; ++pass) {
    int ll = pass * 4 + lq;
    int l = lt + ll;
    int p = l / h_, q = l % h_;
    int j = jt + jj;
    int a = j / 384, rem = j % 384, bb = rem / 128, c = rem % 128;
    int gy = 2 * p + a, gx = 2 * q + bb;
    float v = 0.f;
    if (gy < H_ && gx < W_) v = x[(((size_t)bz * H_ + gy) * W_ + gx) * C_ + c];
    tile[ll][jj] = f2bf(v);
  }
  __syncthreads();
  int lw = t & 31, jq = t >> 5;
  for (int pass = 0; pass < 8; ++pass) {
    int j2 = pass * 8 + jq;
    XpT[((size_t)bz * N9_ + jt + j2) * L_ + lt + lw] = tile[lw][j2];
  }
}

// ---- MFMA GEMM: C[m][n] = sum_k A[m][k]*B[n][k] -------------------------
// 128x128 tile, 4 waves (2x2), BK=32, min-2-phase double buffer,
// global_load_lds(16B) with pre-swizzled source + swizzled ds_read.
template <int OUT>
__global__ __launch_bounds__(256) void gemm_bt(const u16* __restrict__ A,
                                               const u16* __restrict__ B,
                                               void* __restrict__ Cv,
                                               int N, int Kd,
                                               size_t sA, size_t sB, size_t sC) {
  const u16* Ab = A + (size_t)blockIdx.z * sA;
  const u16* Bb = B + (size_t)blockIdx.z * sB;
  int nwg = gridDim.x * gridDim.y;
  int orig = blockIdx.y * gridDim.x + blockIdx.x;
  int wgid = xcd_swz8(orig, nwg);
  int bx = wgid % gridDim.x, by = wgid / gridDim.x;
  int m0 = by * 128, n0 = bx * 128;

  __shared__ char As[2][8192];
  __shared__ char Bs[2][8192];
  int t = threadIdx.x;
  int lane = t & 63, wv = t >> 6, wr = wv >> 1, wc = wv & 1;
  int mrow = lane & 15, kg = lane >> 4;
  f32x4 acc[4][4];
#pragma unroll
  for (int i = 0; i < 4; i++)
#pragma unroll
    for (int j = 0; j < 4; j++) acc[i][j] = (f32x4)(0.0f);

  uint32_t d16 = (uint32_t)t * 16u;
  uint32_t sz = swzb(d16);
  int rowp = (int)(sz >> 6);        // 0..63 permuted row
  int kcp = (int)((sz >> 4) & 3u);  // permuted 16B chunk in row
  const u16* ga0 = Ab + (size_t)(m0 + rowp) * Kd + kcp * 8;
  const u16* ga1 = Ab + (size_t)(m0 + 64 + rowp) * Kd + kcp * 8;
  const u16* gb0 = Bb + (size_t)(n0 + rowp) * Kd + kcp * 8;
  const u16* gb1 = Bb + (size_t)(n0 + 64 + rowp) * Kd + kcp * 8;

  auto STAGE = [&](int buf, int k0) {
    gload16(ga0 + k0, As[buf] + wv * 1024);
    gload16(ga1 + k0, As[buf] + 4096 + wv * 1024);
    gload16(gb0 + k0, Bs[buf] + wv * 1024);
    gload16(gb1 + k0, Bs[buf] + 4096 + wv * 1024);
  };

  int nsteps = Kd >> 5;
  STAGE(0, 0);
  __syncthreads();   // buf0 staged (compiler drains vmcnt before barrier)
  int cur = 0;
  for (int s = 0; s < nsteps; ++s) {
    if (s + 1 < nsteps) STAGE(cur ^ 1, (s + 1) << 5);  // prefetch next tile
    bfrag8 af[4], bf[4];
#pragma unroll
    for (int i = 0; i < 4; i++) {
      uint32_t byte = (uint32_t)(wr * 64 + i * 16 + mrow) * 64u + (uint32_t)kg * 16u;
      af[i] = *(const bfrag8*)(As[cur] + swzb(byte));
    }
#pragma unroll
    for (int i = 0; i < 4; i++) {
      uint32_t byte = (uint32_t)(wc * 64 + i * 16 + mrow) * 64u + (uint32_t)kg * 16u;
      bf[i] = *(const bfrag8*)(Bs[cur] + swzb(byte));
    }
#pragma unroll
    for (int i = 0; i < 4; i++)
#pragma unroll
      for (int j = 0; j < 4; j++)
        acc[i][j] = __builtin_amdgcn_mfma_f32_16x16x32_bf16(af[i], bf[j], acc[i][j], 0, 0, 0);
    __syncthreads();   // drains prefetch (issued before compute) + read-protect
    cur ^= 1;
  }
  // C/D layout: col = lane&15, row = (lane>>4)*4 + reg
#pragma unroll
  for (int i = 0; i < 4; i++)
#pragma unroll
    for (int j = 0; j < 4; j++)
#pragma unroll
      for (int r = 0; r < 4; r++) {
        int gr = m0 + wr * 64 + i * 16 + kg * 4 + r;
        int gc = n0 + wc * 64 + j * 16 + mrow;
        if (OUT == OUT_BF16) {
          ((u16*)Cv)[(size_t)blockIdx.z * sC + (size_t)gr * N + gc] = f2bf(acc[i][j][r]);
        } else {
          ((u16*)Cv)[(size_t)blockIdx.z * sC + (size_t)gr * N + gc] = f2h(acc[i][j][r]);
        }
      }
}

// ---- 9-tap diagonal patch-sum * 1/norm (U fp16 in, V fp32 out) ----------
// 8 outputs/thread. Tap offset o8 + sh*(L+1) = (R+sh)*L + (col+sh); under the
// run-constant row masks R+sh is a valid row, so all 72 loads are issued
// unconditionally at imm offsets (excursions stay inside the workspace) and
// validity is a cndmask on the VALUE. Kills the r4 VGPR-16 serialization.
__global__ __launch_bounds__(256) void k_patchsum(const u16* __restrict__ U,
                                                  float* __restrict__ V,
                                                  const float* __restrict__ ninv,
                                                  int b0) {
  int blk = xcd_swz8(blockIdx.x, gridDim.x);
  int bz = blockIdx.z;
  int o8 = (blk * 256 + (int)threadIdx.x) * 8;
  int R = o8 / L_;
  int col = o8 - R * L_;
  const u16* Ub = U + (size_t)bz * L_ * L_;
  float* Vb = V + (size_t)bz * L_ * L_;
  int hq = R / h_, wq = R % h_, ps = col / h_, qs0 = col % h_;
  bool ra[3], rb[3], ca[3];
#pragma unroll
  for (int a = 0; a < 3; a++) {
    ra[a] = (unsigned)(hq - 1 + a) < (unsigned)h_;
    rb[a] = (unsigned)(wq - 1 + a) < (unsigned)h_;
    ca[a] = (unsigned)(ps - 1 + a) < (unsigned)h_;
  }
  bool md[10];  // md[b+i] = (qs0-1+b+i) in [0,48)
#pragma unroll
  for (int d = 0; d < 10; d++) md[d] = (unsigned)(qs0 - 1 + d) < (unsigned)h_;

  float acc[8];
#pragma unroll
  for (int i = 0; i < 8; i++) acc[i] = 0.f;
#pragma unroll
  for (int a = 0; a < 3; a++) {
#pragma unroll
    for (int b = 0; b < 3; b++) {
      bool tok = ra[a] && ca[a] && rb[b];
      int off = o8 + ((a - 1) * h_ + (b - 1)) * (L_ + 1);
      const u16* tp = Ub + (tok ? off : 0);   // safe: off in-range when tok
#pragma unroll
      for (int i = 0; i < 8; i++) {
        float v = h2f(tp[i]);                 // imm-offset ushort load
        bool ok = tok && md[b + i];
        acc[i] += ok ? v : 0.f;
      }
    }
  }
  const float* nvb = ninv + (size_t)(b0 + bz) * L_ + col;
  f32x4 o0, o1;
#pragma unroll
  for (int i = 0; i < 4; i++) {
    o0[i] = acc[i] * nvb[i];
    o1[i] = acc[i + 4] * nvb[i + 4];
  }
  *(f32x4*)(Vb + o8) = o0;
  *(f32x4*)(Vb + o8 + 4) = o1;
}

// ---- fused fuse1 + fuse2 + masked softmax -> bf16 attention -------------
// Transposed-flat shifts collapse to branch values:
//   T(T(j)-1) = j-48 (jy>0) else j+2255 ; T(T(j)+1) = j+48 (jy<47) else j-2255.
__global__ __launch_bounds__(256) void k_fsm(const float* __restrict__ V1,
                                             const float* __restrict__ mm,
                                             u16* __restrict__ Aout,
                                             int b0) {
  int i = xcd_swz8(blockIdx.x, L_), bz = blockIdx.y;
  int hq = i / h_, wq = i % h_;
  const float* Vb = V1 + (size_t)bz * L_ * L_;
  const float* mmb = mm + (size_t)(b0 + bz) * L_;
  u16* arow = Aout + ((size_t)bz * L_ + i) * L_;
  int t = threadIdx.x;

  uint32_t rowBase[3];
  bool rw0[3], rw1[3], rw2[3];
#pragma unroll
  for (int d2 = 0; d2 < 3; d2++) {
    int TA = wq * h_ + hq + (d2 - 1);
    bool ok = (TA >= 0) && (TA < L_);
    int TAc = ok ? TA : 0;
    int iB = (TAc % h_) * h_ + TAc / h_;
    rowBase[d2] = (uint32_t)(iB * L_);
    rw0[d2] = ok && (iB - 1 >= 0);
    rw1[d2] = ok;
    rw2[d2] = ok && (iB + 1 < L_);
  }

  int jy = t / h_, jx = t % h_;
  float y[9];
  float mx = -3.0e38f;
#pragma unroll
  for (int cc = 0; cc < 9; cc++) {
    int j = cc * 256 + t;
    int jB0 = (jy >= 1) ? (j - h_) : (j + (L_ - h_ - 1));
    int jB1 = j;
    int jB2 = (jy <= h_ - 2) ? (j + h_) : (j - (L_ - h_ - 1));
    bool tb0 = (j > 0), tb2 = (j < L_ - 1);
    float s = 0.f;
    {
      uint32_t oc = rowBase[0] + (uint32_t)jB0;
      bool w0 = rw0[0] && tb0 && (jB0 > 0);
      bool w1 = rw1[0] && tb0;
      bool w2 = rw2[0] && tb0 && (jB0 < L_ - 1);
      float vm = Vb[w0 ? oc - (L_ + 1) : 0u];
      float vc = Vb[w1 ? oc : 0u];
      float vp = Vb[w2 ? oc + (L_ + 1) : 0u];
      s += (w0 ? vm : 0.f) + (w1 ? vc : 0.f) + (w2 ? vp : 0.f);
    }
    {
      uint32_t oc = rowBase[1] + (uint32_t)jB1;
      bool w0 = rw0[1] && (jB1 > 0);
      bool w1 = rw1[1];
      bool w2 = rw2[1] && (jB1 < L_ - 1);
      float vm = Vb[w0 ? oc - (L_ + 1) : 0u];
      float vc = Vb[w1 ? oc : 0u];
      float vp = Vb[w2 ? oc + (L_ + 1) : 0u];
      s += (w0 ? vm : 0.f) + (w1 ? vc : 0.f) + (w2 ? vp : 0.f);
    }
    {
      uint32_t oc = rowBase[2] + (uint32_t)jB2;
      bool w0 = rw0[2] && tb2 && (jB2 > 0);
      bool w1 = rw1[2] && tb2;
      bool w2 = rw2[2] && tb2 && (jB2 < L_ - 1);
      float vm = Vb[w0 ? oc - (L_ + 1) : 0u];
      float vc = Vb[w1 ? oc : 0u];
      float vp = Vb[w2 ? oc + (L_ + 1) : 0u];
      s += (w0 ? vm : 0.f) + (w1 ? vc : 0.f) + (w2 ? vp : 0.f);
    }
    float zv = s * mmb[j] * SCALE_;
    y[cc] = zv;
    mx = fmaxf(mx, zv);
    jx += 256 - 5 * h_;   // +16
    jy += 5;
    if (jx >= h_) { jx -= h_; jy += 1; }
  }

  int lane = t & 63, wid = t >> 6;
  __shared__ float wredm[4];
  __shared__ float wreds[4];
#pragma unroll
  for (int o = 32; o >= 1; o >>= 1) mx = fmaxf(mx, __shfl_xor(mx, o, 64));
  if (lane == 0) wredm[wid] = mx;
  __syncthreads();
  float MX = fmaxf(fmaxf(wredm[0], wredm[1]), fmaxf(wredm[2], wredm[3]));
  float sm = 0.f;
#pragma unroll
  for (int cc = 0; cc < 9; cc++) {
    y[cc] = __expf(y[cc] - MX);
    sm += y[cc];
  }
#pragma unroll
  for (int o = 32; o >= 1; o >>= 1) sm += __shfl_xor(sm, o, 64);
  if (lane == 0) wreds[wid] = sm;
  __syncthreads();
  float inv = 1.0f / (wreds[0] + wreds[1] + wreds[2] + wreds[3]);
#pragma unroll
  for (int cc = 0; cc < 9; cc++) {
    int j = cc * 256 + t;
    arow[j] = f2bf(y[cc] * inv * mmb[j]);
  }
}

// ---- deconv parity-gather scatter (P is bf16) ---------------------------
__global__ __launch_bounds__(256) void k_scatter(const u16* __restrict__ P,
                                                 float* __restrict__ out) {
  int idx = blockIdx.x * 256 + threadIdx.x;
  int c = idx & 127;
  int r = idx >> 7;
  int xx = r % W_; r /= W_;
  int y = r % H_;
  int bz = r / H_;
  const u16* Pb = P + (size_t)bz * L_ * N9_;
  int yo[2], ya[2], ny = 0;
  if (y & 1) { yo[0] = y >> 1; ya[0] = 1; ny = 1; }
  else {
    yo[0] = y >> 1; ya[0] = 0; ny = 1;
    if (y >= 2) { yo[1] = (y >> 1) - 1; ya[1] = 2; ny = 2; }
  }
  int xo[2], xa[2], nx = 0;
  if (xx & 1) { xo[0] = xx >> 1; xa[0] = 1; nx = 1; }
  else {
    xo[0] = xx >> 1; xa[0] = 0; nx = 1;
    if (xx >= 2) { xo[1] = (xx >> 1) - 1; xa[1] = 2; nx = 2; }
  }
  float s = 0.f;
  for (int i = 0; i < ny; i++)
    for (int j = 0; j < nx; j++)
      s += bf2f(Pb[(size_t)(yo[i] * h_ + xo[j]) * N9_ + (ya[i] * 3 + xa[j]) * C_ + c]);
  out[((size_t)bz * H_ + y) * (size_t)W_ * C_ + (size_t)xx * C_ + c] = 0.25f * s;
}

}  // namespace

extern "C" void kernel_launch(void* const* d_in, const int* in_sizes, int n_in,
                              void* d_out, int out_size, void* d_ws, size_t ws_size,
                              hipStream_t stream) {
  (void)in_sizes; (void)n_in; (void)out_size;
  const float* x = (const float*)d_in[0];
  const float* mask = (const float*)d_in[1];
  float* out = (float*)d_out;
  char* ws = (char*)d_ws;

  const size_t szF3 = (size_t)B_ * L_ * K3_ * sizeof(u16);
  const size_t szSm = (size_t)B_ * L_ * sizeof(float);
  const size_t off_F3a = 0;
  const size_t off_F3b = off_F3a + szF3;
  const size_t off_S = off_F3b + szF3;
  const size_t off_md = off_S + szSm;
  const size_t off_mm = off_md + szSm;
  const size_t off_nv = off_mm + szSm;
  const size_t off_fixed_end = off_nv + szSm;

  const size_t perXp = (size_t)N9_ * L_ * sizeof(u16);   // 5.3 MB
  const size_t perU = (size_t)L_ * L_ * sizeof(u16);     // 10.6 MB (fp16)
  const size_t perV = (size_t)L_ * L_ * sizeof(float);   // 21.2 MB (fp32)
  int G = 4;
  while (G > 1 && off_fixed_end + (size_t)G * (perXp + perU + perV) > ws_size) G >>= 1;

  const size_t off_XpT = off_fixed_end;
  const size_t off_U = off_XpT + (size_t)G * perXp;
  const size_t off_V = off_U + (size_t)G * perU;

  u16* F3a = (u16*)(ws + off_F3a);
  u16* F3b = (u16*)(ws + off_F3b);
  float* S = (float*)(ws + off_S);
  float* md = (float*)(ws + off_md);
  float* mm = (float*)(ws + off_mm);
  float* nv = (float*)(ws + off_nv);
  u16* XpT = (u16*)(ws + off_XpT);
  u16* U = (u16*)(ws + off_U);
  float* V = (float*)(ws + off_V);
  u16* Abuf = (u16*)(ws + off_U);   // alias U (U dead after patchsum)
  u16* Pbuf = (u16*)(ws + off_V);   // alias V (V dead after fsm)

  k_down<<<dim3(B_ * L_), dim3(C_), 0, stream>>>(x, F3a, F3b, S);
  k_mask<<<dim3((B_ * L_) / 256), dim3(256), 0, stream>>>(mask, md);
  k_mmnorm<<<dim3((B_ * L_) / 256), dim3(256), 0, stream>>>(S, md, mm, nv);

  for (int sb = 0; sb < B_; sb += G) {
    const float* xs = x + (size_t)sb * H_ * W_ * C_;
    k_xpack<<<dim3(L_ / 32, N9_ / 64, G), dim3(256), 0, stream>>>(xs, XpT);
    gemm_bt<OUT_F16><<<dim3(L_ / 128, L_ / 128, G), dim3(256), 0, stream>>>(
        F3a + (size_t)sb * L_ * K3_, F3b + (size_t)sb * L_ * K3_, (void*)U,
        L_, K3_, (size_t)L_ * K3_, (size_t)L_ * K3_, (size_t)L_ * L_);
    k_patchsum<<<dim3((L_ * L_) / (256 * 8), 1, G), dim3(256), 0, stream>>>(U, V, nv, sb);
    k_fsm<<<dim3(L_, G), dim3(256), 0, stream>>>(V, mm, Abuf, sb);
    gemm_bt<OUT_BF16><<<dim3(N9_ / 128, L_ / 128, G), dim3(256), 0, stream>>>(
        Abuf, XpT, (void*)Pbuf, N9_, L_,
        (size_t)L_ * L_, (size_t)N9_ * L_, (size_t)L_ * N9_);
    k_scatter<<<dim3((G * H_ * W_ * C_) / 256), dim3(256), 0, stream>>>(
        Pbuf, out + (size_t)sb * H_ * W_ * C_);
  }
}

// Round 7
// 221.532 us; speedup vs baseline: 2.0998x; 1.0171x over previous
//
#include <hip/hip_runtime.h>
#include <hip/hip_fp16.h>
#include <stdint.h>
#include <string.h>

// ContextualAttention on MI355X.
// Pipeline:
//  k_down:    x -> (bf16x3 packed F3a/F3b for Gram GEMM) + per-pixel sumsq S
//  k_mask:    mask -> 2x2 avg-pooled md
//  k_mmnorm:  md,S -> mm (valid-patch mask), ninv (1/patch-norm)
//  k_xpack:   x -> XpT[j=(a,b,c)][l=(p,q)] bf16 (deconv weights, transposed for GEMM B)
//  gemm_bt<F16>: U(fp16) = F3a . F3b^T   (Gram, fp32-accurate via bf16x3)
//  k_patchsum:V(fp32)[hw][pq] = 9-tap diag stencil of U * ninv[pq]
//             (8 outputs/thread, b128 vector tap loads, value-masked)
//  k_fsm:     fused fuse1 + fuse2 + masked softmax -> A (bf16)
//  gemm_bt<BF16>: P(bf16) = A . XpT^T
//  k_scatter: out = parity-gather of P / 4

namespace {

constexpr int B_ = 4;
constexpr int H_ = 96;
constexpr int W_ = 96;
constexpr int C_ = 128;
constexpr int h_ = 48;
constexpr int L_ = 2304;   // h_*h_
constexpr int N9_ = 1152;  // 9*C_
constexpr int K3_ = 384;   // 3*C_  bf16x3 packed K
constexpr float SCALE_ = 10.0f;
constexpr float EPS_ = 1e-4f;

constexpr int OUT_F16 = 1;
constexpr int OUT_BF16 = 2;

typedef unsigned short u16;
typedef __attribute__((ext_vector_type(8))) short bfrag8;     // 8 bf16 (4 VGPRs)
typedef __attribute__((ext_vector_type(8))) unsigned short ushort8;  // 16B fp16 vector
typedef __attribute__((ext_vector_type(4))) float f32x4;      // 4 fp32 acc

__device__ __forceinline__ u16 f2bf(float f) {
  uint32_t x;
  __builtin_memcpy(&x, &f, 4);
  uint32_t lsb = (x >> 16) & 1u;
  x += 0x7fffu + lsb;
  return (u16)(x >> 16);
}
__device__ __forceinline__ float bf2f(u16 u) {
  uint32_t v = ((uint32_t)u) << 16;
  float f;
  __builtin_memcpy(&f, &v, 4);
  return f;
}
__device__ __forceinline__ u16 f2h(float f) {
  __half h = __float2half(f);
  u16 u;
  __builtin_memcpy(&u, &h, 2);
  return u;
}
__device__ __forceinline__ float h2f(u16 u) {
  __half h;
  __builtin_memcpy(&h, &u, 2);
  return __half2float(h);
}

// async global(16B/lane) -> LDS (wave-uniform base + lane*16)
__device__ __forceinline__ void gload16(const u16* g, void* l) {
  __builtin_amdgcn_global_load_lds(
      (const __attribute__((address_space(1))) void*)g,
      (__attribute__((address_space(3))) void*)l, 16, 0, 0);
}

// XCD-chunked bijective block swizzle (m204 variant, any nwg)
__device__ __forceinline__ int xcd_swz8(int orig, int nwg) {
  int q = nwg >> 3, r = nwg & 7;
  int xcd = orig & 7, pos = orig >> 3;
  return (xcd < r ? xcd * (q + 1) : r * (q + 1) + (xcd - r) * q) + pos;
}

// LDS byte-offset swizzle (involution): XOR row bits[3:1] onto 16B-slot bits.
__device__ __forceinline__ uint32_t swzb(uint32_t byte) {
  return byte ^ (((byte >> 7) & 7u) << 4);
}

// ---- downscale (2x2 avg) + bf16x3 pack + per-pixel sum of squares -------
__global__ __launch_bounds__(128) void k_down(const float* __restrict__ x,
                                              u16* __restrict__ F3a,
                                              u16* __restrict__ F3b,
                                              float* __restrict__ S) {
  int blk = blockIdx.x;
  int b = blk / L_, l = blk % L_;
  int p = l / h_, q = l % h_;
  int c = threadIdx.x;
  const float* xb = x + (((size_t)b * H_ + 2 * p) * W_ + 2 * q) * C_ + c;
  float v = 0.25f * (xb[0] + xb[C_] + xb[(size_t)W_ * C_] + xb[(size_t)W_ * C_ + C_]);
  u16 hi = f2bf(v);
  u16 lo = f2bf(v - bf2f(hi));
  size_t base = ((size_t)b * L_ + l) * K3_;
  F3a[base + c] = hi; F3a[base + 128 + c] = hi; F3a[base + 256 + c] = lo;
  F3b[base + c] = hi; F3b[base + 128 + c] = lo; F3b[base + 256 + c] = hi;
  __shared__ float red[128];
  red[c] = v * v;
  __syncthreads();
  for (int s2 = 64; s2 > 0; s2 >>= 1) {
    if (c < s2) red[c] += red[c + s2];
    __syncthreads();
  }
  if (c == 0) S[(size_t)b * L_ + l] = red[0];
}

// ---- mask 2x2 avg-pool --------------------------------------------------
__global__ __launch_bounds__(256) void k_mask(const float* __restrict__ mask,
                                              float* __restrict__ md) {
  int i = blockIdx.x * 256 + threadIdx.x;
  int b = i / L_, l = i % L_, p = l / h_, q = l % h_;
  const float* mb = mask + ((size_t)b * H_ + 2 * p) * W_ + 2 * q;
  md[i] = 0.25f * (mb[0] + mb[1] + mb[W_] + mb[W_ + 1]);
}

// ---- valid-patch mask + 1/patch-norm ------------------------------------
__global__ __launch_bounds__(256) void k_mmnorm(const float* __restrict__ S,
                                                const float* __restrict__ md,
                                                float* __restrict__ mm,
                                                float* __restrict__ ninv) {
  int i = blockIdx.x * 256 + threadIdx.x;
  int b = i / L_, l = i % L_, p = l / h_, q = l % h_;
  float ssum = 0.f, msum = 0.f;
#pragma unroll
  for (int a = 0; a < 3; a++) {
    int rp = p - 1 + a;
#pragma unroll
    for (int bb = 0; bb < 3; bb++) {
      int rq = q - 1 + bb;
      bool ok = ((unsigned)rp < (unsigned)h_) && ((unsigned)rq < (unsigned)h_);
      int idx = ok ? (b * L_ + rp * h_ + rq) : 0;
      float sv = S[idx], mv = md[idx];
      if (ok) { ssum += sv; msum += mv; }
    }
  }
  mm[i] = (msum == 0.f) ? 1.f : 0.f;
  float n = fmaxf(sqrtf(ssum), EPS_);
  ninv[i] = 1.f / n;
}

// ---- pack deconv weights transposed: XpT[bz][j=(a,bb,c)][l=(p,q)] -------
__global__ __launch_bounds__(256) void k_xpack(const float* __restrict__ x,
                                               u16* __restrict__ XpT) {
  int lt = blockIdx.x * 32, jt = blockIdx.y * 64, bz = blockIdx.z;
  __shared__ u16 tile[32][65];
  int t = threadIdx.x;
  int jj = t & 63, lq = t >> 6;
  for (int pass = 0; pass < 8; ++pass) {
    int ll = pass * 4 + lq;
    int l = lt + ll;
    int p = l / h_, q = l % h_;
    int j = jt + jj;
    int a = j / 384, rem = j % 384, bb = rem / 128, c = rem % 128;
    int gy = 2 * p + a, gx = 2 * q + bb;
    float v = 0.f;
    if (gy < H_ && gx < W_) v = x[(((size_t)bz * H_ + gy) * W_ + gx) * C_ + c];
    tile[ll][jj] = f2bf(v);
  }
  __syncthreads();
  int lw = t & 31, jq = t >> 5;
  for (int pass = 0; pass < 8; ++pass) {
    int j2 = pass * 8 + jq;
    XpT[((size_t)bz * N9_ + jt + j2) * L_ + lt + lw] = tile[lw][j2];
  }
}

// ---- MFMA GEMM: C[m][n] = sum_k A[m][k]*B[n][k] -------------------------
// 128x128 tile, 4 waves (2x2), BK=32, min-2-phase double buffer,
// global_load_lds(16B) with pre-swizzled source + swizzled ds_read.
template <int OUT>
__global__ __launch_bounds__(256) void gemm_bt(const u16* __restrict__ A,
                                               const u16* __restrict__ B,
                                               void* __restrict__ Cv,
                                               int N, int Kd,
                                               size_t sA, size_t sB, size_t sC) {
  const u16* Ab = A + (size_t)blockIdx.z * sA;
  const u16* Bb = B + (size_t)blockIdx.z * sB;
  int nwg = gridDim.x * gridDim.y;
  int orig = blockIdx.y * gridDim.x + blockIdx.x;
  int wgid = xcd_swz8(orig, nwg);
  int bx = wgid % gridDim.x, by = wgid / gridDim.x;
  int m0 = by * 128, n0 = bx * 128;

  __shared__ char As[2][8192];
  __shared__ char Bs[2][8192];
  int t = threadIdx.x;
  int lane = t & 63, wv = t >> 6, wr = wv >> 1, wc = wv & 1;
  int mrow = lane & 15, kg = lane >> 4;
  f32x4 acc[4][4];
#pragma unroll
  for (int i = 0; i < 4; i++)
#pragma unroll
    for (int j = 0; j < 4; j++) acc[i][j] = (f32x4)(0.0f);

  uint32_t d16 = (uint32_t)t * 16u;
  uint32_t sz = swzb(d16);
  int rowp = (int)(sz >> 6);        // 0..63 permuted row
  int kcp = (int)((sz >> 4) & 3u);  // permuted 16B chunk in row
  const u16* ga0 = Ab + (size_t)(m0 + rowp) * Kd + kcp * 8;
  const u16* ga1 = Ab + (size_t)(m0 + 64 + rowp) * Kd + kcp * 8;
  const u16* gb0 = Bb + (size_t)(n0 + rowp) * Kd + kcp * 8;
  const u16* gb1 = Bb + (size_t)(n0 + 64 + rowp) * Kd + kcp * 8;

  auto STAGE = [&](int buf, int k0) {
    gload16(ga0 + k0, As[buf] + wv * 1024);
    gload16(ga1 + k0, As[buf] + 4096 + wv * 1024);
    gload16(gb0 + k0, Bs[buf] + wv * 1024);
    gload16(gb1 + k0, Bs[buf] + 4096 + wv * 1024);
  };

  int nsteps = Kd >> 5;
  STAGE(0, 0);
  __syncthreads();   // buf0 staged (compiler drains vmcnt before barrier)
  int cur = 0;
  for (int s = 0; s < nsteps; ++s) {
    if (s + 1 < nsteps) STAGE(cur ^ 1, (s + 1) << 5);  // prefetch next tile
    bfrag8 af[4], bf[4];
#pragma unroll
    for (int i = 0; i < 4; i++) {
      uint32_t byte = (uint32_t)(wr * 64 + i * 16 + mrow) * 64u + (uint32_t)kg * 16u;
      af[i] = *(const bfrag8*)(As[cur] + swzb(byte));
    }
#pragma unroll
    for (int i = 0; i < 4; i++) {
      uint32_t byte = (uint32_t)(wc * 64 + i * 16 + mrow) * 64u + (uint32_t)kg * 16u;
      bf[i] = *(const bfrag8*)(Bs[cur] + swzb(byte));
    }
#pragma unroll
    for (int i = 0; i < 4; i++)
#pragma unroll
      for (int j = 0; j < 4; j++)
        acc[i][j] = __builtin_amdgcn_mfma_f32_16x16x32_bf16(af[i], bf[j], acc[i][j], 0, 0, 0);
    __syncthreads();   // drains prefetch (issued before compute) + read-protect
    cur ^= 1;
  }
  // C/D layout: col = lane&15, row = (lane>>4)*4 + reg
#pragma unroll
  for (int i = 0; i < 4; i++)
#pragma unroll
    for (int j = 0; j < 4; j++)
#pragma unroll
      for (int r = 0; r < 4; r++) {
        int gr = m0 + wr * 64 + i * 16 + kg * 4 + r;
        int gc = n0 + wc * 64 + j * 16 + mrow;
        if (OUT == OUT_BF16) {
          ((u16*)Cv)[(size_t)blockIdx.z * sC + (size_t)gr * N + gc] = f2bf(acc[i][j][r]);
        } else {
          ((u16*)Cv)[(size_t)blockIdx.z * sC + (size_t)gr * N + gc] = f2h(acc[i][j][r]);
        }
      }
}

// ---- patchsum tap: 8 contiguous fp16 at flat offset o8 + S*2305 ---------
// off = o8 + S*2305, o8 % 8 == 0 -> off % 8 == S % 8 in {0,1,7}:
//   rem 0: one aligned b128;  rem 1: b128@(off-1) + ushort@(off+7);
//   rem 7: ushort@(off) + b128@(off+1).  Clamp (when !tok) preserves residue.
template <int S>
__device__ __forceinline__ void tap(const u16* __restrict__ Ub, int o8, bool tok,
                                    const bool* md, int b, float* acc) {
  constexpr int REM = ((S % 8) + 8) % 8;
  int off = tok ? (o8 + S * 2305) : (8 + REM);
  float v[8];
  if constexpr (REM == 0) {
    ushort8 w = *(const ushort8*)(Ub + off);
#pragma unroll
    for (int i = 0; i < 8; i++) v[i] = h2f(w[i]);
  } else if constexpr (REM == 1) {
    ushort8 w = *(const ushort8*)(Ub + off - 1);   // elems off-1 .. off+6
    u16 sc = Ub[off + 7];
#pragma unroll
    for (int i = 0; i < 7; i++) v[i] = h2f(w[i + 1]);
    v[7] = h2f(sc);
  } else {  // REM == 7
    u16 sc = Ub[off];
    ushort8 w = *(const ushort8*)(Ub + off + 1);   // elems off+1 .. off+8
    v[0] = h2f(sc);
#pragma unroll
    for (int i = 1; i < 8; i++) v[i] = h2f(w[i - 1]);
  }
#pragma unroll
  for (int i = 0; i < 8; i++) acc[i] += (tok && md[b + i]) ? v[i] : 0.f;
}

// ---- 9-tap diagonal patch-sum * 1/norm (U fp16 in, V fp32 out) ----------
// 8 outputs/thread; per tap one (or two) lane-contiguous vector loads.
__global__ __launch_bounds__(256) void k_patchsum(const u16* __restrict__ U,
                                                  float* __restrict__ V,
                                                  const float* __restrict__ ninv,
                                                  int b0) {
  int blk = xcd_swz8(blockIdx.x, gridDim.x);
  int bz = blockIdx.z;
  int o8 = (blk * 256 + (int)threadIdx.x) * 8;
  int R = o8 / L_;
  int col = o8 - R * L_;
  const u16* Ub = U + (size_t)bz * L_ * L_;
  float* Vb = V + (size_t)bz * L_ * L_;
  int hq = R / h_, wq = R % h_, ps = col / h_, qs0 = col % h_;
  bool ra[3], rb[3], ca[3];
#pragma unroll
  for (int a = 0; a < 3; a++) {
    ra[a] = (unsigned)(hq - 1 + a) < (unsigned)h_;
    rb[a] = (unsigned)(wq - 1 + a) < (unsigned)h_;
    ca[a] = (unsigned)(ps - 1 + a) < (unsigned)h_;
  }
  bool md[10];  // md[b+i] = (qs0-1+b+i) in [0,48); col0 % 8 == 0 -> no qs wrap
#pragma unroll
  for (int d = 0; d < 10; d++) md[d] = (unsigned)(qs0 - 1 + d) < (unsigned)h_;

  float acc[8];
#pragma unroll
  for (int i = 0; i < 8; i++) acc[i] = 0.f;

  bool t0 = ra[0] && ca[0];
  bool t1 = ra[1] && ca[1];
  bool t2 = ra[2] && ca[2];
  tap<-49>(Ub, o8, t0 && rb[0], md, 0, acc);
  tap<-48>(Ub, o8, t0 && rb[1], md, 1, acc);
  tap<-47>(Ub, o8, t0 && rb[2], md, 2, acc);
  tap<-1>(Ub, o8, t1 && rb[0], md, 0, acc);
  tap<0>(Ub, o8, t1 && rb[1], md, 1, acc);
  tap<1>(Ub, o8, t1 && rb[2], md, 2, acc);
  tap<47>(Ub, o8, t2 && rb[0], md, 0, acc);
  tap<48>(Ub, o8, t2 && rb[1], md, 1, acc);
  tap<49>(Ub, o8, t2 && rb[2], md, 2, acc);

  const float* nvb = ninv + (size_t)(b0 + bz) * L_ + col;
  f32x4 o0, o1;
#pragma unroll
  for (int i = 0; i < 4; i++) {
    o0[i] = acc[i] * nvb[i];
    o1[i] = acc[i + 4] * nvb[i + 4];
  }
  *(f32x4*)(Vb + o8) = o0;
  *(f32x4*)(Vb + o8 + 4) = o1;
}

// ---- fused fuse1 + fuse2 + masked softmax -> bf16 attention -------------
// Transposed-flat shifts collapse to branch values:
//   T(T(j)-1) = j-48 (jy>0) else j+2255 ; T(T(j)+1) = j+48 (jy<47) else j-2255.
__global__ __launch_bounds__(256) void k_fsm(const float* __restrict__ V1,
                                             const float* __restrict__ mm,
                                             u16* __restrict__ Aout,
                                             int b0) {
  int i = xcd_swz8(blockIdx.x, L_), bz = blockIdx.y;
  int hq = i / h_, wq = i % h_;
  const float* Vb = V1 + (size_t)bz * L_ * L_;
  const float* mmb = mm + (size_t)(b0 + bz) * L_;
  u16* arow = Aout + ((size_t)bz * L_ + i) * L_;
  int t = threadIdx.x;

  uint32_t rowBase[3];
  bool rw0[3], rw1[3], rw2[3];
#pragma unroll
  for (int d2 = 0; d2 < 3; d2++) {
    int TA = wq * h_ + hq + (d2 - 1);
    bool ok = (TA >= 0) && (TA < L_);
    int TAc = ok ? TA : 0;
    int iB = (TAc % h_) * h_ + TAc / h_;
    rowBase[d2] = (uint32_t)(iB * L_);
    rw0[d2] = ok && (iB - 1 >= 0);
    rw1[d2] = ok;
    rw2[d2] = ok && (iB + 1 < L_);
  }

  int jy = t / h_, jx = t % h_;
  float y[9];
  float mx = -3.0e38f;
#pragma unroll
  for (int cc = 0; cc < 9; cc++) {
    int j = cc * 256 + t;
    int jB0 = (jy >= 1) ? (j - h_) : (j + (L_ - h_ - 1));
    int jB1 = j;
    int jB2 = (jy <= h_ - 2) ? (j + h_) : (j - (L_ - h_ - 1));
    bool tb0 = (j > 0), tb2 = (j < L_ - 1);
    float s = 0.f;
    {
      uint32_t oc = rowBase[0] + (uint32_t)jB0;
      bool w0 = rw0[0] && tb0 && (jB0 > 0);
      bool w1 = rw1[0] && tb0;
      bool w2 = rw2[0] && tb0 && (jB0 < L_ - 1);
      float vm = Vb[w0 ? oc - (L_ + 1) : 0u];
      float vc = Vb[w1 ? oc : 0u];
      float vp = Vb[w2 ? oc + (L_ + 1) : 0u];
      s += (w0 ? vm : 0.f) + (w1 ? vc : 0.f) + (w2 ? vp : 0.f);
    }
    {
      uint32_t oc = rowBase[1] + (uint32_t)jB1;
      bool w0 = rw0[1] && (jB1 > 0);
      bool w1 = rw1[1];
      bool w2 = rw2[1] && (jB1 < L_ - 1);
      float vm = Vb[w0 ? oc - (L_ + 1) : 0u];
      float vc = Vb[w1 ? oc : 0u];
      float vp = Vb[w2 ? oc + (L_ + 1) : 0u];
      s += (w0 ? vm : 0.f) + (w1 ? vc : 0.f) + (w2 ? vp : 0.f);
    }
    {
      uint32_t oc = rowBase[2] + (uint32_t)jB2;
      bool w0 = rw0[2] && tb2 && (jB2 > 0);
      bool w1 = rw1[2] && tb2;
      bool w2 = rw2[2] && tb2 && (jB2 < L_ - 1);
      float vm = Vb[w0 ? oc - (L_ + 1) : 0u];
      float vc = Vb[w1 ? oc : 0u];
      float vp = Vb[w2 ? oc + (L_ + 1) : 0u];
      s += (w0 ? vm : 0.f) + (w1 ? vc : 0.f) + (w2 ? vp : 0.f);
    }
    float zv = s * mmb[j] * SCALE_;
    y[cc] = zv;
    mx = fmaxf(mx, zv);
    jx += 256 - 5 * h_;   // +16
    jy += 5;
    if (jx >= h_) { jx -= h_; jy += 1; }
  }

  int lane = t & 63, wid = t >> 6;
  __shared__ float wredm[4];
  __shared__ float wreds[4];
#pragma unroll
  for (int o = 32; o >= 1; o >>= 1) mx = fmaxf(mx, __shfl_xor(mx, o, 64));
  if (lane == 0) wredm[wid] = mx;
  __syncthreads();
  float MX = fmaxf(fmaxf(wredm[0], wredm[1]), fmaxf(wredm[2], wredm[3]));
  float sm = 0.f;
#pragma unroll
  for (int cc = 0; cc < 9; cc++) {
    y[cc] = __expf(y[cc] - MX);
    sm += y[cc];
  }
#pragma unroll
  for (int o = 32; o >= 1; o >>= 1) sm += __shfl_xor(sm, o, 64);
  if (lane == 0) wreds[wid] = sm;
  __syncthreads();
  float inv = 1.0f / (wreds[0] + wreds[1] + wreds[2] + wreds[3]);
#pragma unroll
  for (int cc = 0; cc < 9; cc++) {
    int j = cc * 256 + t;
    arow[j] = f2bf(y[cc] * inv * mmb[j]);
  }
}

// ---- deconv parity-gather scatter (P is bf16) ---------------------------
__global__ __launch_bounds__(256) void k_scatter(const u16* __restrict__ P,
                                                 float* __restrict__ out) {
  int idx = blockIdx.x * 256 + threadIdx.x;
  int c = idx & 127;
  int r = idx >> 7;
  int xx = r % W_; r /= W_;
  int y = r % H_;
  int bz = r / H_;
  const u16* Pb = P + (size_t)bz * L_ * N9_;
  int yo[2], ya[2], ny = 0;
  if (y & 1) { yo[0] = y >> 1; ya[0] = 1; ny = 1; }
  else {
    yo[0] = y >> 1; ya[0] = 0; ny = 1;
    if (y >= 2) { yo[1] = (y >> 1) - 1; ya[1] = 2; ny = 2; }
  }
  int xo[2], xa[2], nx = 0;
  if (xx & 1) { xo[0] = xx >> 1; xa[0] = 1; nx = 1; }
  else {
    xo[0] = xx >> 1; xa[0] = 0; nx = 1;
    if (xx >= 2) { xo[1] = (xx >> 1) - 1; xa[1] = 2; nx = 2; }
  }
  float s = 0.f;
  for (int i = 0; i < ny; i++)
    for (int j = 0; j < nx; j++)
      s += bf2f(Pb[(size_t)(yo[i] * h_ + xo[j]) * N9_ + (ya[i] * 3 + xa[j]) * C_ + c]);
  out[((size_t)bz * H_ + y) * (size_t)W_ * C_ + (size_t)xx * C_ + c] = 0.25f * s;
}

}  // namespace

extern "C" void kernel_launch(void* const* d_in, const int* in_sizes, int n_in,
                              void* d_out, int out_size, void* d_ws, size_t ws_size,
                              hipStream_t stream) {
  (void)in_sizes; (void)n_in; (void)out_size;
  const float* x = (const float*)d_in[0];
  const float* mask = (const float*)d_in[1];
  float* out = (float*)d_out;
  char* ws = (char*)d_ws;

  const size_t szF3 = (size_t)B_ * L_ * K3_ * sizeof(u16);
  const size_t szSm = (size_t)B_ * L_ * sizeof(float);
  const size_t off_F3a = 0;
  const size_t off_F3b = off_F3a + szF3;
  const size_t off_S = off_F3b + szF3;
  const size_t off_md = off_S + szSm;
  const size_t off_mm = off_md + szSm;
  const size_t off_nv = off_mm + szSm;
  const size_t off_fixed_end = off_nv + szSm;

  const size_t perXp = (size_t)N9_ * L_ * sizeof(u16);   // 5.3 MB
  const size_t perU = (size_t)L_ * L_ * sizeof(u16);     // 10.6 MB (fp16)
  const size_t perV = (size_t)L_ * L_ * sizeof(float);   // 21.2 MB (fp32)
  int G = 4;
  while (G > 1 && off_fixed_end + (size_t)G * (perXp + perU + perV) > ws_size) G >>= 1;

  const size_t off_XpT = off_fixed_end;
  const size_t off_U = off_XpT + (size_t)G * perXp;
  const size_t off_V = off_U + (size_t)G * perU;

  u16* F3a = (u16*)(ws + off_F3a);
  u16* F3b = (u16*)(ws + off_F3b);
  float* S = (float*)(ws + off_S);
  float* md = (float*)(ws + off_md);
  float* mm = (float*)(ws + off_mm);
  float* nv = (float*)(ws + off_nv);
  u16* XpT = (u16*)(ws + off_XpT);
  u16* U = (u16*)(ws + off_U);
  float* V = (float*)(ws + off_V);
  u16* Abuf = (u16*)(ws + off_U);   // alias U (U dead after patchsum)
  u16* Pbuf = (u16*)(ws + off_V);   // alias V (V dead after fsm)

  k_down<<<dim3(B_ * L_), dim3(C_), 0, stream>>>(x, F3a, F3b, S);
  k_mask<<<dim3((B_ * L_) / 256), dim3(256), 0, stream>>>(mask, md);
  k_mmnorm<<<dim3((B_ * L_) / 256), dim3(256), 0, stream>>>(S, md, mm, nv);

  for (int sb = 0; sb < B_; sb += G) {
    const float* xs = x + (size_t)sb * H_ * W_ * C_;
    k_xpack<<<dim3(L_ / 32, N9_ / 64, G), dim3(256), 0, stream>>>(xs, XpT);
    gemm_bt<OUT_F16><<<dim3(L_ / 128, L_ / 128, G), dim3(256), 0, stream>>>(
        F3a + (size_t)sb * L_ * K3_, F3b + (size_t)sb * L_ * K3_, (void*)U,
        L_, K3_, (size_t)L_ * K3_, (size_t)L_ * K3_, (size_t)L_ * L_);
    k_patchsum<<<dim3((L_ * L_) / (256 * 8), 1, G), dim3(256), 0, stream>>>(U, V, nv, sb);
    k_fsm<<<dim3(L_, G), dim3(256), 0, stream>>>(V, mm, Abuf, sb);
    gemm_bt<OUT_BF16><<<dim3(N9_ / 128, L_ / 128, G), dim3(256), 0, stream>>>(
        Abuf, XpT, (void*)Pbuf, N9_, L_,
        (size_t)L_ * L_, (size_t)N9_ * L_, (size_t)L_ * N9_);
    k_scatter<<<dim3((G * H_ * W_ * C_) / 256), dim3(256), 0, stream>>>(
        Pbuf, out + (size_t)sb * H_ * W_ * C_);
  }
}

// Round 9
// 204.063 us; speedup vs baseline: 2.2796x; 1.0856x over previous
//
#include <hip/hip_runtime.h>
#include <hip/hip_fp16.h>
#include <stdint.h>
#include <string.h>

// ContextualAttention on MI355X.
// Pipeline:
//  k_down:    x -> (bf16x3 packed F3a/F3b for Gram GEMM) + per-pixel sumsq S
//  k_mask:    mask -> 2x2 avg-pooled md
//  k_mmnorm:  md,S -> mm (valid-patch mask), ninv (1/patch-norm)
//  k_xpack:   x -> XpT[j=(a,b,c)][l=(p,q)] bf16 (deconv weights, transposed for GEMM B)
//  gemm_bt<F16>: U(fp16) = F3a . F3b^T   (Gram, fp32-accurate via bf16x3)
//  k_patchsum:V(fp16)[hw][pq] = 9-tap diag stencil of U * ninv[pq]
//  k_fsm:     fused fuse1 + fuse2 + masked softmax -> A (bf16)
//  gemm_bt<BF16>: P(bf16) = A . XpT^T
//  k_scatter: out = parity-gather of P / 4  (2 channels/thread)
// gemm_bt: proven 128x128 4-wave structure (R4-R7), 2-phase dbuf,
// global_load_lds(16B) with both-sides XOR swizzle.

namespace {

constexpr int B_ = 4;
constexpr int H_ = 96;
constexpr int W_ = 96;
constexpr int C_ = 128;
constexpr int h_ = 48;
constexpr int L_ = 2304;   // h_*h_
constexpr int N9_ = 1152;  // 9*C_
constexpr int K3_ = 384;   // 3*C_  bf16x3 packed K
constexpr float SCALE_ = 10.0f;
constexpr float EPS_ = 1e-4f;

constexpr int OUT_F16 = 1;
constexpr int OUT_BF16 = 2;

typedef unsigned short u16;
typedef __attribute__((ext_vector_type(8))) short bfrag8;            // 8 bf16
typedef __attribute__((ext_vector_type(8))) unsigned short ushort8;  // 16B
typedef __attribute__((ext_vector_type(4))) float f32x4;
typedef __attribute__((ext_vector_type(2))) float f32x2;

__device__ __forceinline__ u16 f2bf(float f) {
  uint32_t x;
  __builtin_memcpy(&x, &f, 4);
  uint32_t lsb = (x >> 16) & 1u;
  x += 0x7fffu + lsb;
  return (u16)(x >> 16);
}
__device__ __forceinline__ float bf2f(u16 u) {
  uint32_t v = ((uint32_t)u) << 16;
  float f;
  __builtin_memcpy(&f, &v, 4);
  return f;
}
__device__ __forceinline__ u16 f2h(float f) {
  __half h = __float2half(f);
  u16 u;
  __builtin_memcpy(&u, &h, 2);
  return u;
}
__device__ __forceinline__ float h2f(u16 u) {
  __half h;
  __builtin_memcpy(&h, &u, 2);
  return __half2float(h);
}

// async global(16B/lane) -> LDS (wave-uniform base + lane*16)
__device__ __forceinline__ void gload16(const u16* g, void* l) {
  __builtin_amdgcn_global_load_lds(
      (const __attribute__((address_space(1))) void*)g,
      (__attribute__((address_space(3))) void*)l, 16, 0, 0);
}

// XCD-chunked bijective block swizzle (m204 variant, any nwg)
__device__ __forceinline__ int xcd_swz8(int orig, int nwg) {
  int q = nwg >> 3, r = nwg & 7;
  int xcd = orig & 7, pos = orig >> 3;
  return (xcd < r ? xcd * (q + 1) : r * (q + 1) + (xcd - r) * q) + pos;
}

// LDS byte-offset swizzle (involution): XOR row bits[3:1] onto 16B-slot bits.
__device__ __forceinline__ uint32_t swzb(uint32_t byte) {
  return byte ^ (((byte >> 7) & 7u) << 4);
}

// ---- downscale (2x2 avg) + bf16x3 pack + per-pixel sum of squares -------
__global__ __launch_bounds__(128) void k_down(const float* __restrict__ x,
                                              u16* __restrict__ F3a,
                                              u16* __restrict__ F3b,
                                              float* __restrict__ S) {
  int blk = blockIdx.x;
  int b = blk / L_, l = blk % L_;
  int p = l / h_, q = l % h_;
  int c = threadIdx.x;
  const float* xb = x + (((size_t)b * H_ + 2 * p) * W_ + 2 * q) * C_ + c;
  float v = 0.25f * (xb[0] + xb[C_] + xb[(size_t)W_ * C_] + xb[(size_t)W_ * C_ + C_]);
  u16 hi = f2bf(v);
  u16 lo = f2bf(v - bf2f(hi));
  size_t base = ((size_t)b * L_ + l) * K3_;
  // A-side: [hi, hi, lo]; B-side: [hi, lo, hi] -> A.B^T = hi.hi + hi.lo + lo.hi
  F3a[base + c] = hi; F3a[base + 128 + c] = hi; F3a[base + 256 + c] = lo;
  F3b[base + c] = hi; F3b[base + 128 + c] = lo; F3b[base + 256 + c] = hi;
  float ss = v * v;
#pragma unroll
  for (int o = 32; o >= 1; o >>= 1) ss += __shfl_xor(ss, o, 64);
  __shared__ float w2[2];
  if ((c & 63) == 0) w2[c >> 6] = ss;
  __syncthreads();
  if (c == 0) S[(size_t)b * L_ + l] = w2[0] + w2[1];
}

// ---- mask 2x2 avg-pool --------------------------------------------------
__global__ __launch_bounds__(256) void k_mask(const float* __restrict__ mask,
                                              float* __restrict__ md) {
  int i = blockIdx.x * 256 + threadIdx.x;
  int b = i / L_, l = i % L_, p = l / h_, q = l % h_;
  const float* mb = mask + ((size_t)b * H_ + 2 * p) * W_ + 2 * q;
  md[i] = 0.25f * (mb[0] + mb[1] + mb[W_] + mb[W_ + 1]);
}

// ---- valid-patch mask + 1/patch-norm ------------------------------------
__global__ __launch_bounds__(256) void k_mmnorm(const float* __restrict__ S,
                                                const float* __restrict__ md,
                                                float* __restrict__ mm,
                                                float* __restrict__ ninv) {
  int i = blockIdx.x * 256 + threadIdx.x;
  int b = i / L_, l = i % L_, p = l / h_, q = l % h_;
  float ssum = 0.f, msum = 0.f;
#pragma unroll
  for (int a = 0; a < 3; a++) {
    int rp = p - 1 + a;
#pragma unroll
    for (int bb = 0; bb < 3; bb++) {
      int rq = q - 1 + bb;
      bool ok = ((unsigned)rp < (unsigned)h_) && ((unsigned)rq < (unsigned)h_);
      int idx = ok ? (b * L_ + rp * h_ + rq) : 0;
      float sv = S[idx], mv = md[idx];
      if (ok) { ssum += sv; msum += mv; }
    }
  }
  mm[i] = (msum == 0.f) ? 1.f : 0.f;
  float n = fmaxf(sqrtf(ssum), EPS_);
  ninv[i] = 1.f / n;
}

// ---- pack deconv weights transposed: XpT[bz][j=(a,bb,c)][l=(p,q)] -------
__global__ __launch_bounds__(256) void k_xpack(const float* __restrict__ x,
                                               u16* __restrict__ XpT) {
  int lt = blockIdx.x * 32, jt = blockIdx.y * 64, bz = blockIdx.z;
  __shared__ u16 tile[32][65];
  int t = threadIdx.x;
  int jj = t & 63, lq = t >> 6;
  for (int pass = 0; pass < 8; ++pass) {
    int ll = pass * 4 + lq;
    int l = lt + ll;
    int p = l / h_, q = l % h_;
    int j = jt + jj;
    int a = j / 384, rem = j % 384, bb = rem / 128, c = rem % 128;
    int gy = 2 * p + a, gx = 2 * q + bb;
    float v = 0.f;
    if (gy < H_ && gx < W_) v = x[(((size_t)bz * H_ + gy) * W_ + gx) * C_ + c];
    tile[ll][jj] = f2bf(v);
  }
  __syncthreads();
  int lw = t & 31, jq = t >> 5;
  for (int pass = 0; pass < 8; ++pass) {
    int j2 = pass * 8 + jq;
    XpT[((size_t)bz * N9_ + jt + j2) * L_ + lt + lw] = tile[lw][j2];
  }
}

// ---- MFMA GEMM: C[m][n] = sum_k A[m][k]*B[n][k] (R7-proven structure) ----
template <int OUT>
__global__ __launch_bounds__(256) void gemm_bt(const u16* __restrict__ A,
                                               const u16* __restrict__ B,
                                               void* __restrict__ Cv,
                                               int N, int Kd,
                                               size_t sA, size_t sB, size_t sC) {
  const u16* Ab = A + (size_t)blockIdx.z * sA;
  const u16* Bb = B + (size_t)blockIdx.z * sB;
  int nwg = gridDim.x * gridDim.y;
  int orig = blockIdx.y * gridDim.x + blockIdx.x;
  int wgid = xcd_swz8(orig, nwg);
  int bx = wgid % gridDim.x, by = wgid / gridDim.x;
  int m0 = by * 128, n0 = bx * 128;

  __shared__ char As[2][8192];
  __shared__ char Bs[2][8192];
  int t = threadIdx.x;
  int lane = t & 63, wv = t >> 6, wr = wv >> 1, wc = wv & 1;
  int mrow = lane & 15, kg = lane >> 4;
  f32x4 acc[4][4];
#pragma unroll
  for (int i = 0; i < 4; i++)
#pragma unroll
    for (int j = 0; j < 4; j++) acc[i][j] = (f32x4)(0.0f);

  uint32_t d16 = (uint32_t)t * 16u;
  uint32_t sz = swzb(d16);
  int rowp = (int)(sz >> 6);        // 0..63 permuted row
  int kcp = (int)((sz >> 4) & 3u);  // permuted 16B chunk in row
  const u16* ga0 = Ab + (size_t)(m0 + rowp) * Kd + kcp * 8;
  const u16* ga1 = Ab + (size_t)(m0 + 64 + rowp) * Kd + kcp * 8;
  const u16* gb0 = Bb + (size_t)(n0 + rowp) * Kd + kcp * 8;
  const u16* gb1 = Bb + (size_t)(n0 + 64 + rowp) * Kd + kcp * 8;

  auto STAGE = [&](int buf, int k0) {
    gload16(ga0 + k0, As[buf] + wv * 1024);
    gload16(ga1 + k0, As[buf] + 4096 + wv * 1024);
    gload16(gb0 + k0, Bs[buf] + wv * 1024);
    gload16(gb1 + k0, Bs[buf] + 4096 + wv * 1024);
  };

  int nsteps = Kd >> 5;
  STAGE(0, 0);
  __syncthreads();   // buf0 staged (compiler drains vmcnt before barrier)
  int cur = 0;
  for (int s = 0; s < nsteps; ++s) {
    if (s + 1 < nsteps) STAGE(cur ^ 1, (s + 1) << 5);  // prefetch next tile
    bfrag8 af[4], bf[4];
#pragma unroll
    for (int i = 0; i < 4; i++) {
      uint32_t byte = (uint32_t)(wr * 64 + i * 16 + mrow) * 64u + (uint32_t)kg * 16u;
      af[i] = *(const bfrag8*)(As[cur] + swzb(byte));
    }
#pragma unroll
    for (int i = 0; i < 4; i++) {
      uint32_t byte = (uint32_t)(wc * 64 + i * 16 + mrow) * 64u + (uint32_t)kg * 16u;
      bf[i] = *(const bfrag8*)(Bs[cur] + swzb(byte));
    }
#pragma unroll
    for (int i = 0; i < 4; i++)
#pragma unroll
      for (int j = 0; j < 4; j++)
        acc[i][j] = __builtin_amdgcn_mfma_f32_16x16x32_bf16(af[i], bf[j], acc[i][j], 0, 0, 0);
    __syncthreads();   // drains prefetch (issued before compute) + read-protect
    cur ^= 1;
  }
  // C/D layout: col = lane&15, row = (lane>>4)*4 + reg
#pragma unroll
  for (int i = 0; i < 4; i++)
#pragma unroll
    for (int j = 0; j < 4; j++)
#pragma unroll
      for (int r = 0; r < 4; r++) {
        int gr = m0 + wr * 64 + i * 16 + kg * 4 + r;
        int gc = n0 + wc * 64 + j * 16 + mrow;
        if (OUT == OUT_BF16) {
          ((u16*)Cv)[(size_t)blockIdx.z * sC + (size_t)gr * N + gc] = f2bf(acc[i][j][r]);
        } else {
          ((u16*)Cv)[(size_t)blockIdx.z * sC + (size_t)gr * N + gc] = f2h(acc[i][j][r]);
        }
      }
}

// ---- patchsum tap: 8 contiguous fp16 at flat offset o8 + S*2305 ---------
template <int S>
__device__ __forceinline__ void tap(const u16* __restrict__ Ub, int o8, bool tok,
                                    const bool* md, int b, float* acc) {
  constexpr int REM = ((S % 8) + 8) % 8;
  int off = tok ? (o8 + S * 2305) : (8 + REM);
  float v[8];
  if constexpr (REM == 0) {
    ushort8 w = *(const ushort8*)(Ub + off);
#pragma unroll
    for (int i = 0; i < 8; i++) v[i] = h2f(w[i]);
  } else if constexpr (REM == 1) {
    ushort8 w = *(const ushort8*)(Ub + off - 1);
    u16 sc = Ub[off + 7];
#pragma unroll
    for (int i = 0; i < 7; i++) v[i] = h2f(w[i + 1]);
    v[7] = h2f(sc);
  } else {  // REM == 7
    u16 sc = Ub[off];
    ushort8 w = *(const ushort8*)(Ub + off + 1);
    v[0] = h2f(sc);
#pragma unroll
    for (int i = 1; i < 8; i++) v[i] = h2f(w[i - 1]);
  }
#pragma unroll
  for (int i = 0; i < 8; i++) acc[i] += (tok && md[b + i]) ? v[i] : 0.f;
}

// ---- 9-tap diagonal patch-sum * 1/norm (U fp16 in, V fp16 out) ----------
__global__ __launch_bounds__(256) void k_patchsum(const u16* __restrict__ U,
                                                  u16* __restrict__ V,
                                                  const float* __restrict__ ninv,
                                                  int b0) {
  int blk = xcd_swz8(blockIdx.x, gridDim.x);
  int bz = blockIdx.z;
  int o8 = (blk * 256 + (int)threadIdx.x) * 8;
  int R = o8 / L_;
  int col = o8 - R * L_;
  const u16* Ub = U + (size_t)bz * L_ * L_;
  u16* Vb = V + (size_t)bz * L_ * L_;
  int hq = R / h_, wq = R % h_, ps = col / h_, qs0 = col % h_;
  bool ra[3], rb[3], ca[3];
#pragma unroll
  for (int a = 0; a < 3; a++) {
    ra[a] = (unsigned)(hq - 1 + a) < (unsigned)h_;
    rb[a] = (unsigned)(wq - 1 + a) < (unsigned)h_;
    ca[a] = (unsigned)(ps - 1 + a) < (unsigned)h_;
  }
  bool md[10];
#pragma unroll
  for (int d = 0; d < 10; d++) md[d] = (unsigned)(qs0 - 1 + d) < (unsigned)h_;

  float acc[8];
#pragma unroll
  for (int i = 0; i < 8; i++) acc[i] = 0.f;

  bool t0 = ra[0] && ca[0];
  bool t1 = ra[1] && ca[1];
  bool t2 = ra[2] && ca[2];
  tap<-49>(Ub, o8, t0 && rb[0], md, 0, acc);
  tap<-48>(Ub, o8, t0 && rb[1], md, 1, acc);
  tap<-47>(Ub, o8, t0 && rb[2], md, 2, acc);
  tap<-1>(Ub, o8, t1 && rb[0], md, 0, acc);
  tap<0>(Ub, o8, t1 && rb[1], md, 1, acc);
  tap<1>(Ub, o8, t1 && rb[2], md, 2, acc);
  tap<47>(Ub, o8, t2 && rb[0], md, 0, acc);
  tap<48>(Ub, o8, t2 && rb[1], md, 1, acc);
  tap<49>(Ub, o8, t2 && rb[2], md, 2, acc);

  const float* nvb = ninv + (size_t)(b0 + bz) * L_ + col;
  ushort8 ov;
#pragma unroll
  for (int i = 0; i < 8; i++) ov[i] = f2h(acc[i] * nvb[i]);
  *(ushort8*)(Vb + o8) = ov;
}

// ---- fused fuse1 + fuse2 + masked softmax -> bf16 attention -------------
// Transposed-flat shifts collapse to branch values:
//   T(T(j)-1) = j-48 (jy>0) else j+2255 ; T(T(j)+1) = j+48 (jy<47) else j-2255.
__global__ __launch_bounds__(256) void k_fsm(const u16* __restrict__ V1,
                                             const float* __restrict__ mm,
                                             u16* __restrict__ Aout,
                                             int b0) {
  int i = xcd_swz8(blockIdx.x, L_), bz = blockIdx.y;
  int hq = i / h_, wq = i % h_;
  const u16* Vb = V1 + (size_t)bz * L_ * L_;
  const float* mmb = mm + (size_t)(b0 + bz) * L_;
  u16* arow = Aout + ((size_t)bz * L_ + i) * L_;
  int t = threadIdx.x;

  uint32_t rowBase[3];
  bool rw0[3], rw1[3], rw2[3];
#pragma unroll
  for (int d2 = 0; d2 < 3; d2++) {
    int TA = wq * h_ + hq + (d2 - 1);
    bool ok = (TA >= 0) && (TA < L_);
    int TAc = ok ? TA : 0;
    int iB = (TAc % h_) * h_ + TAc / h_;
    rowBase[d2] = (uint32_t)(iB * L_);
    rw0[d2] = ok && (iB - 1 >= 0);
    rw1[d2] = ok;
    rw2[d2] = ok && (iB + 1 < L_);
  }

  int jy = t / h_, jx = t % h_;
  float y[9];
  float mx = -3.0e38f;
#pragma unroll
  for (int cc = 0; cc < 9; cc++) {
    int j = cc * 256 + t;
    int jB0 = (jy >= 1) ? (j - h_) : (j + (L_ - h_ - 1));
    int jB1 = j;
    int jB2 = (jy <= h_ - 2) ? (j + h_) : (j - (L_ - h_ - 1));
    bool tb0 = (j > 0), tb2 = (j < L_ - 1);
    float s = 0.f;
    {
      uint32_t oc = rowBase[0] + (uint32_t)jB0;
      bool w0 = rw0[0] && tb0 && (jB0 > 0);
      bool w1 = rw1[0] && tb0;
      bool w2 = rw2[0] && tb0 && (jB0 < L_ - 1);
      float vm = h2f(Vb[w0 ? oc - (L_ + 1) : 0u]);
      float vc = h2f(Vb[w1 ? oc : 0u]);
      float vp = h2f(Vb[w2 ? oc + (L_ + 1) : 0u]);
      s += (w0 ? vm : 0.f) + (w1 ? vc : 0.f) + (w2 ? vp : 0.f);
    }
    {
      uint32_t oc = rowBase[1] + (uint32_t)jB1;
      bool w0 = rw0[1] && (jB1 > 0);
      bool w1 = rw1[1];
      bool w2 = rw2[1] && (jB1 < L_ - 1);
      float vm = h2f(Vb[w0 ? oc - (L_ + 1) : 0u]);
      float vc = h2f(Vb[w1 ? oc : 0u]);
      float vp = h2f(Vb[w2 ? oc + (L_ + 1) : 0u]);
      s += (w0 ? vm : 0.f) + (w1 ? vc : 0.f) + (w2 ? vp : 0.f);
    }
    {
      uint32_t oc = rowBase[2] + (uint32_t)jB2;
      bool w0 = rw0[2] && tb2 && (jB2 > 0);
      bool w1 = rw1[2] && tb2;
      bool w2 = rw2[2] && tb2 && (jB2 < L_ - 1);
      float vm = h2f(Vb[w0 ? oc - (L_ + 1) : 0u]);
      float vc = h2f(Vb[w1 ? oc : 0u]);
      float vp = h2f(Vb[w2 ? oc + (L_ + 1) : 0u]);
      s += (w0 ? vm : 0.f) + (w1 ? vc : 0.f) + (w2 ? vp : 0.f);
    }
    float zv = s * mmb[j] * SCALE_;
    y[cc] = zv;
    mx = fmaxf(mx, zv);
    jx += 256 - 5 * h_;   // +16
    jy += 5;
    if (jx >= h_) { jx -= h_; jy += 1; }
  }

  int lane = t & 63, wid = t >> 6;
  __shared__ float wredm[4];
  __shared__ float wreds[4];
#pragma unroll
  for (int o = 32; o >= 1; o >>= 1) mx = fmaxf(mx, __shfl_xor(mx, o, 64));
  if (lane == 0) wredm[wid] = mx;
  __syncthreads();
  float MX = fmaxf(fmaxf(wredm[0], wredm[1]), fmaxf(wredm[2], wredm[3]));
  float sm = 0.f;
#pragma unroll
  for (int cc = 0; cc < 9; cc++) {
    y[cc] = __expf(y[cc] - MX);
    sm += y[cc];
  }
#pragma unroll
  for (int o = 32; o >= 1; o >>= 1) sm += __shfl_xor(sm, o, 64);
  if (lane == 0) wreds[wid] = sm;
  __syncthreads();
  float inv = 1.0f / (wreds[0] + wreds[1] + wreds[2] + wreds[3]);
#pragma unroll
  for (int cc = 0; cc < 9; cc++) {
    int j = cc * 256 + t;
    arow[j] = f2bf(y[cc] * inv * mmb[j]);
  }
}

// ---- deconv parity-gather scatter (P bf16, 2 channels/thread) -----------
__global__ __launch_bounds__(256) void k_scatter(const u16* __restrict__ P,
                                                 float* __restrict__ out) {
  int idx = blockIdx.x * 256 + threadIdx.x;   // over B*H*W*64
  int c2 = idx & 63;
  int r = idx >> 6;
  int xx = r % W_; r /= W_;
  int y = r % H_;
  int bz = r / H_;
  const u16* Pb = P + (size_t)bz * L_ * N9_;
  int yo[2], ya[2], ny = 0;
  if (y & 1) { yo[0] = y >> 1; ya[0] = 1; ny = 1; }
  else {
    yo[0] = y >> 1; ya[0] = 0; ny = 1;
    if (y >= 2) { yo[1] = (y >> 1) - 1; ya[1] = 2; ny = 2; }
  }
  int xo[2], xa[2], nx = 0;
  if (xx & 1) { xo[0] = xx >> 1; xa[0] = 1; nx = 1; }
  else {
    xo[0] = xx >> 1; xa[0] = 0; nx = 1;
    if (xx >= 2) { xo[1] = (xx >> 1) - 1; xa[1] = 2; nx = 2; }
  }
  float s0 = 0.f, s1 = 0.f;
  for (int i = 0; i < ny; i++)
    for (int j = 0; j < nx; j++) {
      size_t off = (size_t)(yo[i] * h_ + xo[j]) * N9_ + (ya[i] * 3 + xa[j]) * C_ + 2 * c2;
      uint32_t w = *(const uint32_t*)(Pb + off);
      s0 += bf2f((u16)(w & 0xffffu));
      s1 += bf2f((u16)(w >> 16));
    }
  f32x2 o;
  o[0] = 0.25f * s0;
  o[1] = 0.25f * s1;
  *(f32x2*)(out + ((size_t)bz * H_ + y) * (size_t)W_ * C_ + (size_t)xx * C_ + 2 * c2) = o;
}

}  // namespace

extern "C" void kernel_launch(void* const* d_in, const int* in_sizes, int n_in,
                              void* d_out, int out_size, void* d_ws, size_t ws_size,
                              hipStream_t stream) {
  (void)in_sizes; (void)n_in; (void)out_size;
  const float* x = (const float*)d_in[0];
  const float* mask = (const float*)d_in[1];
  float* out = (float*)d_out;
  char* ws = (char*)d_ws;

  const size_t szF3 = (size_t)B_ * L_ * K3_ * sizeof(u16);
  const size_t szSm = (size_t)B_ * L_ * sizeof(float);
  const size_t off_F3a = 0;
  const size_t off_F3b = off_F3a + szF3;
  const size_t off_S = off_F3b + szF3;
  const size_t off_md = off_S + szSm;
  const size_t off_mm = off_md + szSm;
  const size_t off_nv = off_mm + szSm;
  const size_t off_fixed_end = off_nv + szSm;

  const size_t perXp = (size_t)N9_ * L_ * sizeof(u16);   // 5.3 MB
  const size_t perU = (size_t)L_ * L_ * sizeof(u16);     // 10.6 MB (fp16)
  const size_t perV = (size_t)L_ * L_ * sizeof(u16);     // 10.6 MB (fp16)
  int G = 4;
  while (G > 1 && off_fixed_end + (size_t)G * (perXp + perU + perV) > ws_size) G >>= 1;

  const size_t off_XpT = off_fixed_end;
  const size_t off_U = off_XpT + (size_t)G * perXp;
  const size_t off_V = off_U + (size_t)G * perU;

  u16* F3a = (u16*)(ws + off_F3a);
  u16* F3b = (u16*)(ws + off_F3b);
  float* S = (float*)(ws + off_S);
  float* md = (float*)(ws + off_md);
  float* mm = (float*)(ws + off_mm);
  float* nv = (float*)(ws + off_nv);
  u16* XpT = (u16*)(ws + off_XpT);
  u16* U = (u16*)(ws + off_U);
  u16* V = (u16*)(ws + off_V);
  u16* Abuf = (u16*)(ws + off_U);   // alias U (U dead after patchsum)
  u16* Pbuf = (u16*)(ws + off_V);   // alias V (V dead after fsm)

  k_down<<<dim3(B_ * L_), dim3(C_), 0, stream>>>(x, F3a, F3b, S);
  k_mask<<<dim3((B_ * L_) / 256), dim3(256), 0, stream>>>(mask, md);
  k_mmnorm<<<dim3((B_ * L_) / 256), dim3(256), 0, stream>>>(S, md, mm, nv);

  for (int sb = 0; sb < B_; sb += G) {
    const float* xs = x + (size_t)sb * H_ * W_ * C_;
    k_xpack<<<dim3(L_ / 32, N9_ / 64, G), dim3(256), 0, stream>>>(xs, XpT);
    gemm_bt<OUT_F16><<<dim3(L_ / 128, L_ / 128, G), dim3(256), 0, stream>>>(
        F3a + (size_t)sb * L_ * K3_, F3b + (size_t)sb * L_ * K3_, (void*)U,
        L_, K3_, (size_t)L_ * K3_, (size_t)L_ * K3_, (size_t)L_ * L_);
    k_patchsum<<<dim3((L_ * L_) / (256 * 8), 1, G), dim3(256), 0, stream>>>(U, V, nv, sb);
    k_fsm<<<dim3(L_, G), dim3(256), 0, stream>>>(V, mm, Abuf, sb);
    gemm_bt<OUT_BF16><<<dim3(N9_ / 128, L_ / 128, G), dim3(256), 0, stream>>>(
        Abuf, XpT, (void*)Pbuf, N9_, L_,
        (size_t)L_ * L_, (size_t)N9_ * L_, (size_t)L_ * N9_);
    k_scatter<<<dim3((G * H_ * W_ * C_ / 2) / 256), dim3(256), 0, stream>>>(
        Pbuf, out + (size_t)sb * H_ * W_ * C_);
  }
}